// Round 1
// baseline (627.781 us; speedup 1.0000x reference)
//
#include <hip/hip_runtime.h>
#include <cstdint>
#include <cstddef>

#define DEV __device__ __forceinline__

typedef __bf16 bf16x8 __attribute__((ext_vector_type(8)));
typedef float f32x4 __attribute__((ext_vector_type(4)));

#define NEG_VAL -10000.0f

DEV unsigned int f2bf(float f) {
    unsigned int u = __float_as_uint(f);
    return (u + 0x7FFFu + ((u >> 16) & 1u)) >> 16;   // RNE to bf16, returned in low 16 bits
}
DEV unsigned int pk2(float a, float b) { return f2bf(a) | (f2bf(b) << 16); }

// ---------------------------------------------------------------------------
// Kernel 1: cast conv weights fp32 -> bf16, chunked+swizzled layout:
// wbc[plane p(12)][c(24)][col(256)][granule g'(4)][8 bf16], g = g' ^ (col&3)
// plane 0-2: cw3 j=0..2; 3-6: cw4; 7-11: cw5
// ---------------------------------------------------------------------------
__global__ void cast_w_kernel(const float* __restrict__ cw3,
                              const float* __restrict__ cw4,
                              const float* __restrict__ cw5,
                              unsigned short* __restrict__ wbc) {
    int tid = blockIdx.x * blockDim.x + threadIdx.x;
    if (tid >= 12 * 24 * 256 * 4) return;
    int gp  = tid & 3;
    int col = (tid >> 2) & 255;
    int c   = (tid >> 10) % 24;
    int p   = tid / (24 * 256 * 4);
    int g = gp ^ (col & 3);
    int sz, j; const float* W;
    if (p < 3)      { sz = 3; j = p;     W = cw3; }
    else if (p < 7) { sz = 4; j = p - 3; W = cw4; }
    else            { sz = 5; j = p - 7; W = cw5; }
    const float* src = W + ((size_t)col * sz + j) * 768 + c * 32 + g * 8;
    float4 a = *(const float4*)(src);
    float4 b = *(const float4*)(src + 4);
    uint4 pk = make_uint4(pk2(a.x, a.y), pk2(a.z, a.w), pk2(b.x, b.y), pk2(b.z, b.w));
    reinterpret_cast<uint4*>(wbc)[tid] = pk;
}

// ---------------------------------------------------------------------------
// Kernel 2: fused embedding-gather + conv (MFMA bf16) + bias + relu + maxpool
// block = (n-group of 4, conv size). M=256 (4n x 64 pos), N=256 filters,
// K = sz*768 looped as 24 e-chunks x sz window offsets.
// 8 waves: wave = (mw = n_local in [0,4), nw in [0,2) = 128-col half)
// ---------------------------------------------------------------------------
__global__ __launch_bounds__(512, 2) void conv_pool_kernel(
    const int* __restrict__ ids,          // (512, 64)
    const float* __restrict__ emb,        // (50000, 768)
    const unsigned short* __restrict__ wbc,
    const float* __restrict__ cb3, const float* __restrict__ cb4,
    const float* __restrict__ cb5,
    float* __restrict__ para)             // (512, 768): [conv3|conv4|conv5]
{
    __shared__ unsigned short Xlds[256 * 32];   // [row][32 e, granule-swizzled]
    __shared__ unsigned short Blds[256 * 32];   // [col][32 k, granule-swizzled]

    int bx  = blockIdx.x;
    int szi = bx % 3;
    int n0  = (bx / 3) * 4;
    int sz  = 3 + szi;
    int pbase = (szi == 0) ? 0 : (szi == 1 ? 3 : 7);
    const float* cb = (szi == 0) ? cb3 : (szi == 1 ? cb4 : cb5);

    int tid  = threadIdx.x;
    int lane = tid & 63;
    int wid  = tid >> 6;
    int mw   = wid >> 1;     // n_local
    int nw   = wid & 1;      // 128-col half

    // staging assignment: row = tid>>1 (0..255), half = tid&1 (16 floats each)
    int srow  = tid >> 1;
    int shalf = tid & 1;
    int sid   = ids[(n0 + (srow >> 6)) * 64 + (srow & 63)];
    const float* embrow = emb + (size_t)sid * 768 + shalf * 16;

    f32x4 acc[4][8];
    #pragma unroll
    for (int a = 0; a < 4; a++)
        #pragma unroll
        for (int t = 0; t < 8; t++) acc[a][t] = (f32x4){0.f, 0.f, 0.f, 0.f};

    for (int c = 0; c < 24; c++) {
        for (int j = 0; j < sz; j++) {
            __syncthreads();    // previous step's LDS readers done
            if (j == 0) {
                const float* s = embrow + c * 32;
                float4 v0 = *(const float4*)(s);
                float4 v1 = *(const float4*)(s + 4);
                float4 v2 = *(const float4*)(s + 8);
                float4 v3 = *(const float4*)(s + 12);
                uint4 p0 = make_uint4(pk2(v0.x, v0.y), pk2(v0.z, v0.w),
                                      pk2(v1.x, v1.y), pk2(v1.z, v1.w));
                uint4 p1 = make_uint4(pk2(v2.x, v2.y), pk2(v2.z, v2.w),
                                      pk2(v3.x, v3.y), pk2(v3.z, v3.w));
                int key = srow & 3;
                *(uint4*)&Xlds[srow * 32 + (((2 * shalf)     ^ key) * 8)] = p0;
                *(uint4*)&Xlds[srow * 32 + (((2 * shalf + 1) ^ key) * 8)] = p1;
            }
            {   // stage B plane (pbase+j, c): 16KB linear copy (pre-swizzled)
                const uint4* src = reinterpret_cast<const uint4*>(
                    wbc + (size_t)((pbase + j) * 24 + c) * 8192);
                uint4* dst = reinterpret_cast<uint4*>(Blds);
                dst[tid]       = src[tid];
                dst[tid + 512] = src[tid + 512];
            }
            __syncthreads();

            bf16x8 af[4];
            #pragma unroll
            for (int a = 0; a < 4; a++) {
                int p = 16 * a + (lane & 15);
                int pj = p + j; if (pj > 63) pj = 63;   // invalid windows masked later
                int xr = 64 * mw + pj;
                af[a] = *reinterpret_cast<const bf16x8*>(
                    &Xlds[xr * 32 + (((lane >> 4) ^ (xr & 3)) * 8)]);
            }
            bf16x8 bfr[8];
            #pragma unroll
            for (int t = 0; t < 8; t++) {
                int col = 128 * nw + 16 * t + (lane & 15);
                bfr[t] = *reinterpret_cast<const bf16x8*>(
                    &Blds[col * 32 + (((lane >> 4) ^ (col & 3)) * 8)]);
            }
            #pragma unroll
            for (int a = 0; a < 4; a++)
                #pragma unroll
                for (int t = 0; t < 8; t++)
                    acc[a][t] = __builtin_amdgcn_mfma_f32_16x16x32_bf16(
                        af[a], bfr[t], acc[a][t], 0, 0, 0);
        }
    }

    // epilogue: relu(acc+bias), mask invalid windows, max over positions
    int n = n0 + mw;
    int pmax = 64 - sz;
    #pragma unroll
    for (int t = 0; t < 8; t++) {
        int colb = 128 * nw + 16 * t;
        float bias = cb[colb + (lane & 15)];
        float m = 0.0f;   // relu >= 0, so 0 is a safe identity over valid rows
        #pragma unroll
        for (int a = 0; a < 4; a++) {
            #pragma unroll
            for (int r = 0; r < 4; r++) {
                int p = 16 * a + (lane >> 4) * 4 + r;
                float v = acc[a][t][r] + bias;
                v = v > 0.f ? v : 0.f;
                if (p <= pmax) m = v > m ? v : m;
            }
        }
        m = fmaxf(m, __shfl_xor(m, 16));
        m = fmaxf(m, __shfl_xor(m, 32));
        if (lane < 16)
            para[(size_t)n * 768 + szi * 256 + colb + lane] = m;
    }
}

// ---------------------------------------------------------------------------
// Kernel 3: LSTM input projection: gates[dir][t][b][j] = x @ Wih.T + bih + bhh
// block = (dir, t); 256 threads, one j each; x rows staged in LDS.
// xmode 0: x = para, row index b*64+t (din=768); xmode 1: x rows t*8+b.
// ---------------------------------------------------------------------------
__global__ void gemm_in_kernel(const float* __restrict__ x, int xmode, int din,
                               const float* __restrict__ WihF,
                               const float* __restrict__ bihF,
                               const float* __restrict__ bhhF,
                               const float* __restrict__ WihB,
                               const float* __restrict__ bihB,
                               const float* __restrict__ bhhB,
                               float* __restrict__ gates) {
    int bx  = blockIdx.x;
    int dir = bx >> 6;
    int t   = bx & 63;
    const float* Wih = dir ? WihB : WihF;
    const float* bih = dir ? bihB : bihF;
    const float* bhh = dir ? bhhB : bhhF;
    extern __shared__ float xs[];    // 8 * din
    int tid = threadIdx.x;
    for (int i = tid; i < 8 * din; i += 256) {
        int b = i / din, e = i % din;
        xs[i] = xmode ? x[((size_t)t * 8 + b) * din + e]
                      : x[((size_t)b * 64 + t) * din + e];
    }
    __syncthreads();
    float accb[8];
    float bias = bih[tid] + bhh[tid];
    #pragma unroll
    for (int b = 0; b < 8; b++) accb[b] = bias;
    const float* wrow = Wih + (size_t)tid * din;
    for (int e = 0; e < din; e += 4) {
        float4 w = *(const float4*)(wrow + e);
        #pragma unroll
        for (int b = 0; b < 8; b++) {
            const float* xr = xs + b * din + e;
            accb[b] += w.x * xr[0] + w.y * xr[1] + w.z * xr[2] + w.w * xr[3];
        }
    }
    #pragma unroll
    for (int b = 0; b < 8; b++)
        gates[(((size_t)dir * 64 + t) * 8 + b) * 256 + tid] = accb[b];
}

// ---------------------------------------------------------------------------
// Kernel 4: LSTM recurrence, one block per direction. Whh row stationary in
// VGPRs (64/thread); h,c in LDS. thread = (j = tid&255, bh = tid>>8 -> b,b+4)
// ---------------------------------------------------------------------------
__global__ __launch_bounds__(1024) void lstm_rec_kernel(
    const float* __restrict__ gates,    // (2,64,8,256)
    const float* __restrict__ WhhF, const float* __restrict__ WhhB, // (256,64)
    float* __restrict__ hout)           // (64,8,128)
{
    int dir = blockIdx.x;
    const float* Whh = dir ? WhhB : WhhF;
    const float* gin = gates + (size_t)dir * 64 * 8 * 256;

    __shared__ float h_lds[8][64];
    __shared__ float c_lds[8][64];
    __shared__ float g_lds[8][256];

    int tid = threadIdx.x;
    int j   = tid & 255;
    int bh  = tid >> 8;     // 0..3

    float w[64];
    #pragma unroll
    for (int e4 = 0; e4 < 16; e4++) {
        float4 v = *(const float4*)(Whh + (size_t)j * 64 + e4 * 4);
        w[e4 * 4 + 0] = v.x; w[e4 * 4 + 1] = v.y;
        w[e4 * 4 + 2] = v.z; w[e4 * 4 + 3] = v.w;
    }
    if (tid < 512) {
        int b = tid >> 6, e = tid & 63;
        h_lds[b][e] = 0.f; c_lds[b][e] = 0.f;
    }
    __syncthreads();

    for (int step = 0; step < 64; step++) {
        int t = dir ? (63 - step) : step;
        #pragma unroll
        for (int bb = 0; bb < 2; bb++) {
            int b = bh + bb * 4;
            float acc = gin[((size_t)t * 8 + b) * 256 + j];
            const float4* hb4 = reinterpret_cast<const float4*>(&h_lds[b][0]);
            #pragma unroll
            for (int e4 = 0; e4 < 16; e4++) {
                float4 hv = hb4[e4];
                acc += w[e4 * 4 + 0] * hv.x + w[e4 * 4 + 1] * hv.y +
                       w[e4 * 4 + 2] * hv.z + w[e4 * 4 + 3] * hv.w;
            }
            g_lds[b][j] = acc;
        }
        __syncthreads();
        if (tid < 512) {
            int b = tid >> 6, hh = tid & 63;
            float gi = g_lds[b][hh];
            float gf = g_lds[b][64 + hh];
            float gg = g_lds[b][128 + hh];
            float go = g_lds[b][192 + hh];
            float si = 1.f / (1.f + expf(-gi));
            float sf = 1.f / (1.f + expf(-gf));
            float so = 1.f / (1.f + expf(-go));
            float cc = sf * c_lds[b][hh] + si * tanhf(gg);
            float hv = so * tanhf(cc);
            c_lds[b][hh] = cc;
            h_lds[b][hh] = hv;
            hout[((size_t)t * 8 + b) * 128 + dir * 64 + hh] = hv;
        }
        __syncthreads();
    }
}

// ---------------------------------------------------------------------------
// Kernel 5: feats (linear) + CRF forward scan + gold score, single block
// ---------------------------------------------------------------------------
__global__ __launch_bounds__(512) void crf_kernel(
    const float* __restrict__ h1,       // (64,8,128)
    const float* __restrict__ lin_w,    // (5,128)
    const float* __restrict__ lin_b,    // (5)
    const float* __restrict__ mask,     // (64,8)
    const int* __restrict__ tags,       // (64,8)
    const float* __restrict__ trans,    // (5,5)
    float* __restrict__ out) {
    __shared__ float feats[64][8][5];
    __shared__ float fwd_s[8], gold_s[8];
    __shared__ float tr[25], trE[5], lb[5];
    int tid = threadIdx.x;
    if (tid < 25) tr[tid] = trans[tid];
    if (tid < 5) { trE[tid] = trans[4 * 5 + tid]; lb[tid] = lin_b[tid]; }
    __syncthreads();

    for (int o = tid; o < 64 * 8 * 5; o += 512) {
        int i = o % 5; int b = (o / 5) & 7; int t = o / 40;
        const float* h = h1 + ((size_t)t * 8 + b) * 128;
        const float* w = lin_w + i * 128;
        float d = 0.f;
        for (int e = 0; e < 128; e++) d += h[e] * w[e];
        float m = mask[t * 8 + b];
        feats[t][b][i] = (m * d + lb[i]) * m;
    }
    __syncthreads();

    if (tid < 40) {    // wave 0, lane = b*5+i
        int b = tid / 5, i = tid % 5;
        float alpha = (i == 0) ? 0.f : NEG_VAL;    // SOS = 0
        float trow[5];
        #pragma unroll
        for (int j2 = 0; j2 < 5; j2++) trow[j2] = tr[i * 5 + j2];
        for (int t = 0; t < 64; t++) {
            float s0, s1, s2, s3, s4;
            s0 = __shfl(alpha, b * 5 + 0, 64) + trow[0];
            s1 = __shfl(alpha, b * 5 + 1, 64) + trow[1];
            s2 = __shfl(alpha, b * 5 + 2, 64) + trow[2];
            s3 = __shfl(alpha, b * 5 + 3, 64) + trow[3];
            s4 = __shfl(alpha, b * 5 + 4, 64) + trow[4];
            float mx = fmaxf(fmaxf(fmaxf(s0, s1), fmaxf(s2, s3)), s4);
            float sum = expf(s0 - mx) + expf(s1 - mx) + expf(s2 - mx) +
                        expf(s3 - mx) + expf(s4 - mx);
            float lse = mx + logf(sum) + feats[t][b][i];
            float mt = mask[t * 8 + b];
            alpha = mt * lse + (1.f - mt) * alpha;
        }
        float v = alpha + trE[i];
        float m0 = __shfl(v, b * 5 + 0, 64);
        float m1 = __shfl(v, b * 5 + 1, 64);
        float m2 = __shfl(v, b * 5 + 2, 64);
        float m3 = __shfl(v, b * 5 + 3, 64);
        float m4 = __shfl(v, b * 5 + 4, 64);
        float mx = fmaxf(fmaxf(fmaxf(m0, m1), fmaxf(m2, m3)), m4);
        float sum = expf(m0 - mx) + expf(m1 - mx) + expf(m2 - mx) +
                    expf(m3 - mx) + expf(m4 - mx);
        if (i == 0) fwd_s[b] = mx + logf(sum);
    }
    if (tid < 8) {
        int b = tid;
        float g = 0.f, lenf = 0.f;
        int prev = 0;   // SOS
        for (int t = 0; t < 64; t++) {
            int tg = tags[t * 8 + b];
            float mt = mask[t * 8 + b];
            g += (feats[t][b][tg] + tr[tg * 5 + prev]) * mt;
            lenf += mt;
            prev = tg;
        }
        int len = (int)lenf;
        int last = (len == 0) ? 0 : tags[(len - 1) * 8 + b];
        g += trE[last];
        gold_s[b] = g;
    }
    __syncthreads();
    if (tid == 0) {
        float s = 0.f;
        for (int b = 0; b < 8; b++) s += fwd_s[b] - gold_s[b];
        out[0] = s;
    }
}

// ---------------------------------------------------------------------------
extern "C" void kernel_launch(void* const* d_in, const int* in_sizes, int n_in,
                              void* d_out, int out_size, void* d_ws, size_t ws_size,
                              hipStream_t stream) {
    const int*   ids   = (const int*)d_in[0];
    const int*   tags  = (const int*)d_in[1];
    const float* mask  = (const float*)d_in[2];
    // d_in[3] = para_len (unused by reference)
    const float* emb   = (const float*)d_in[4];
    const float* cw3   = (const float*)d_in[5];
    const float* cb3   = (const float*)d_in[6];
    const float* cw4   = (const float*)d_in[7];
    const float* cb4   = (const float*)d_in[8];
    const float* cw5   = (const float*)d_in[9];
    const float* cb5   = (const float*)d_in[10];
    const float* Wih0f = (const float*)d_in[11];
    const float* Whh0f = (const float*)d_in[12];
    const float* bih0f = (const float*)d_in[13];
    const float* bhh0f = (const float*)d_in[14];
    const float* Wih0b = (const float*)d_in[15];
    const float* Whh0b = (const float*)d_in[16];
    const float* bih0b = (const float*)d_in[17];
    const float* bhh0b = (const float*)d_in[18];
    const float* Wih1f = (const float*)d_in[19];
    const float* Whh1f = (const float*)d_in[20];
    const float* bih1f = (const float*)d_in[21];
    const float* bhh1f = (const float*)d_in[22];
    const float* Wih1b = (const float*)d_in[23];
    const float* Whh1b = (const float*)d_in[24];
    const float* bih1b = (const float*)d_in[25];
    const float* bhh1b = (const float*)d_in[26];
    const float* lin_w = (const float*)d_in[27];
    const float* lin_b = (const float*)d_in[28];
    const float* trans = (const float*)d_in[29];

    char* ws = (char*)d_ws;
    unsigned short* wbc = (unsigned short*)ws;                 // 4,718,592 B
    float* para  = (float*)(ws + 4718592);                     // 1,572,864 B
    float* gates = (float*)(ws + 4718592 + 1572864);           // 1,048,576 B
    float* h0    = (float*)(ws + 4718592 + 1572864 + 1048576); //   262,144 B
    float* h1    = (float*)(ws + 4718592 + 1572864 + 1048576 + 262144);

    hipLaunchKernelGGL(cast_w_kernel, dim3(1152), dim3(256), 0, stream,
                       cw3, cw4, cw5, wbc);
    hipLaunchKernelGGL(conv_pool_kernel, dim3(384), dim3(512), 0, stream,
                       ids, emb, wbc, cb3, cb4, cb5, para);
    hipLaunchKernelGGL(gemm_in_kernel, dim3(128), dim3(256), 8 * 768 * 4, stream,
                       para, 0, 768, Wih0f, bih0f, bhh0f, Wih0b, bih0b, bhh0b, gates);
    hipLaunchKernelGGL(lstm_rec_kernel, dim3(2), dim3(1024), 0, stream,
                       gates, Whh0f, Whh0b, h0);
    hipLaunchKernelGGL(gemm_in_kernel, dim3(128), dim3(256), 8 * 128 * 4, stream,
                       h0, 1, 128, Wih1f, bih1f, bhh1f, Wih1b, bih1b, bhh1b, gates);
    hipLaunchKernelGGL(lstm_rec_kernel, dim3(2), dim3(1024), 0, stream,
                       gates, Whh1f, Whh1b, h1);
    hipLaunchKernelGGL(crf_kernel, dim3(1), dim3(512), 0, stream,
                       h1, lin_w, lin_b, mask, tags, trans, (float*)d_out);
}

// Round 2
// 491.866 us; speedup vs baseline: 1.2763x; 1.2763x over previous
//
#include <hip/hip_runtime.h>
#include <cstdint>
#include <cstddef>

#define DEV __device__ __forceinline__

typedef __bf16 bf16x8 __attribute__((ext_vector_type(8)));
typedef float f32x4 __attribute__((ext_vector_type(4)));

#define NEG_VAL -10000.0f

DEV unsigned int f2bf(float f) {
    unsigned int u = __float_as_uint(f);
    return (u + 0x7FFFu + ((u >> 16) & 1u)) >> 16;   // RNE to bf16
}
DEV unsigned int pk2(float a, float b) { return f2bf(a) | (f2bf(b) << 16); }

DEV void gload_lds16(const void* g, void* l) {
    __builtin_amdgcn_global_load_lds(
        (const __attribute__((address_space(1))) void*)g,
        (__attribute__((address_space(3))) void*)l, 16, 0, 0);
}

DEV float sigf(float x)  { return __builtin_amdgcn_rcpf(1.f + __expf(-x)); }
DEV float tanhff(float x){ return 2.f * __builtin_amdgcn_rcpf(1.f + __expf(-2.f * x)) - 1.f; }

// ---------------------------------------------------------------------------
// Kernel 1: cast conv weights fp32 -> bf16, chunked+swizzled:
// wbc[plane p(12)][c(24)][col(256)][slot g'(4)][8 bf16], content granule
// g = g' ^ ((col>>1)&3)  (2-way-free bank key for ds_read_b128)
// ---------------------------------------------------------------------------
__global__ void cast_w_kernel(const float* __restrict__ cw3,
                              const float* __restrict__ cw4,
                              const float* __restrict__ cw5,
                              unsigned short* __restrict__ wbc) {
    int tid = blockIdx.x * blockDim.x + threadIdx.x;
    if (tid >= 12 * 24 * 256 * 4) return;
    int gp  = tid & 3;
    int col = (tid >> 2) & 255;
    int c   = (tid >> 10) % 24;
    int p   = tid / (24 * 256 * 4);
    int g = gp ^ ((col >> 1) & 3);
    int sz, j; const float* W;
    if (p < 3)      { sz = 3; j = p;     W = cw3; }
    else if (p < 7) { sz = 4; j = p - 3; W = cw4; }
    else            { sz = 5; j = p - 7; W = cw5; }
    const float* src = W + ((size_t)col * sz + j) * 768 + c * 32 + g * 8;
    float4 a = *(const float4*)(src);
    float4 b = *(const float4*)(src + 4);
    uint4 pk = make_uint4(pk2(a.x, a.y), pk2(a.z, a.w), pk2(b.x, b.y), pk2(b.z, b.w));
    reinterpret_cast<uint4*>(wbc)[tid] = pk;
}

// ---------------------------------------------------------------------------
// Kernel 2: fused embed-gather + conv (MFMA bf16) + bias + relu + maxpool.
// Double-buffered X (per-c) and B (per-step, global_load_lds), 1 barrier/step.
// ---------------------------------------------------------------------------
__global__ __launch_bounds__(512, 2) void conv_pool_kernel(
    const int* __restrict__ ids,
    const float* __restrict__ emb,
    const unsigned short* __restrict__ wbc,
    const float* __restrict__ cb3, const float* __restrict__ cb4,
    const float* __restrict__ cb5,
    float* __restrict__ para)
{
    __shared__ unsigned short Xlds[2][256 * 32];
    __shared__ unsigned short Blds[2][256 * 32];

    int bx  = blockIdx.x;
    int szi = bx % 3;
    int n0  = (bx / 3) * 4;
    int sz  = 3 + szi;
    int pbase = (szi == 0) ? 0 : (szi == 1 ? 3 : 7);
    const float* cb = (szi == 0) ? cb3 : (szi == 1 ? cb4 : cb5);

    int tid  = threadIdx.x;
    int lane = tid & 63;
    int wid  = tid >> 6;
    int mw   = wid >> 1;
    int nw   = wid & 1;
    int l15  = lane & 15;
    int q    = lane >> 4;

    int srow  = tid >> 1;
    int shalf = tid & 1;
    int sid   = ids[(n0 + (srow >> 6)) * 64 + (srow & 63)];
    const float* embrow = emb + (size_t)sid * 768 + shalf * 16;
    int skey = (srow >> 1) & 3;

    f32x4 acc[4][8];
    #pragma unroll
    for (int a = 0; a < 4; a++)
        #pragma unroll
        for (int t = 0; t < 8; t++) acc[a][t] = (f32x4){0.f, 0.f, 0.f, 0.f};

    // prologue: X(c=0) -> Xlds[0], issue B(step 0) -> Blds[0]
    {
        float4 v0 = ((const float4*)embrow)[0];
        float4 v1 = ((const float4*)embrow)[1];
        float4 v2 = ((const float4*)embrow)[2];
        float4 v3 = ((const float4*)embrow)[3];
        uint4 p0 = make_uint4(pk2(v0.x, v0.y), pk2(v0.z, v0.w),
                              pk2(v1.x, v1.y), pk2(v1.z, v1.w));
        uint4 p1 = make_uint4(pk2(v2.x, v2.y), pk2(v2.z, v2.w),
                              pk2(v3.x, v3.y), pk2(v3.z, v3.w));
        *(uint4*)&Xlds[0][srow * 32 + (((2 * shalf)     ^ skey) * 8)] = p0;
        *(uint4*)&Xlds[0][srow * 32 + (((2 * shalf + 1) ^ skey) * 8)] = p1;
        const unsigned short* bs = wbc + (size_t)(pbase * 24) * 8192;
        gload_lds16(bs + tid * 8,        &Blds[0][tid * 8]);
        gload_lds16(bs + 4096 + tid * 8, &Blds[0][4096 + tid * 8]);
    }

    int S = sz * 24;
    int c = 0, j = 0;
    for (int s = 0; s < S; ++s) {
        __syncthreads();   // B(s) landed (vmcnt drain), X(c) visible

        int jn = j + 1, cn = c;
        if (jn == sz) { jn = 0; cn = c + 1; }
        if (s + 1 < S) {
            const unsigned short* bs =
                wbc + (size_t)((pbase + jn) * 24 + cn) * 8192;
            gload_lds16(bs + tid * 8,        &Blds[(s + 1) & 1][tid * 8]);
            gload_lds16(bs + 4096 + tid * 8, &Blds[(s + 1) & 1][4096 + tid * 8]);
        }
        bool doX = (j == sz - 1) && (c + 1 < 24);
        float4 e0, e1, e2, e3;
        if (doX) {
            const float* sp = embrow + (c + 1) * 32;
            e0 = ((const float4*)sp)[0];
            e1 = ((const float4*)sp)[1];
            e2 = ((const float4*)sp)[2];
            e3 = ((const float4*)sp)[3];
        }

        const unsigned short* Xb = Xlds[c & 1];
        const unsigned short* Bb = Blds[s & 1];
        bf16x8 af[4];
        #pragma unroll
        for (int a = 0; a < 4; a++) {
            int pj = 16 * a + l15 + j; if (pj > 63) pj = 63;
            int xr = 64 * mw + pj;
            af[a] = *reinterpret_cast<const bf16x8*>(
                &Xb[xr * 32 + ((q ^ ((xr >> 1) & 3)) * 8)]);
        }
        bf16x8 bfr[8];
        #pragma unroll
        for (int t = 0; t < 8; t++) {
            int col = 128 * nw + 16 * t + l15;
            bfr[t] = *reinterpret_cast<const bf16x8*>(
                &Bb[col * 32 + ((q ^ ((col >> 1) & 3)) * 8)]);
        }
        #pragma unroll
        for (int a = 0; a < 4; a++)
            #pragma unroll
            for (int t = 0; t < 8; t++)
                acc[a][t] = __builtin_amdgcn_mfma_f32_16x16x32_bf16(
                    af[a], bfr[t], acc[a][t], 0, 0, 0);

        if (doX) {
            uint4 p0 = make_uint4(pk2(e0.x, e0.y), pk2(e0.z, e0.w),
                                  pk2(e1.x, e1.y), pk2(e1.z, e1.w));
            uint4 p1 = make_uint4(pk2(e2.x, e2.y), pk2(e2.z, e2.w),
                                  pk2(e3.x, e3.y), pk2(e3.z, e3.w));
            unsigned short* Xw = Xlds[(c + 1) & 1];
            *(uint4*)&Xw[srow * 32 + (((2 * shalf)     ^ skey) * 8)] = p0;
            *(uint4*)&Xw[srow * 32 + (((2 * shalf + 1) ^ skey) * 8)] = p1;
        }
        c = cn; j = jn;
    }

    // epilogue
    int n = n0 + mw;
    int pmax = 64 - sz;
    #pragma unroll
    for (int t = 0; t < 8; t++) {
        int colb = 128 * nw + 16 * t;
        float bias = cb[colb + l15];
        float m = 0.0f;
        #pragma unroll
        for (int a = 0; a < 4; a++) {
            #pragma unroll
            for (int r = 0; r < 4; r++) {
                int p = 16 * a + q * 4 + r;
                float v = acc[a][t][r] + bias;
                v = v > 0.f ? v : 0.f;
                if (p <= pmax) m = v > m ? v : m;
            }
        }
        m = fmaxf(m, __shfl_xor(m, 16));
        m = fmaxf(m, __shfl_xor(m, 32));
        if (lane < 16)
            para[(size_t)n * 768 + szi * 256 + colb + lane] = m;
    }
}

// ---------------------------------------------------------------------------
// Kernel 3: LSTM input projection. Output layout: gates[dir][t][hh][g][b]
// (matches lstm_rec's MFMA C/D row/col mapping).
// ---------------------------------------------------------------------------
__global__ void gemm_in_kernel(const float* __restrict__ x, int xmode, int din,
                               const float* __restrict__ WihF,
                               const float* __restrict__ bihF,
                               const float* __restrict__ bhhF,
                               const float* __restrict__ WihB,
                               const float* __restrict__ bihB,
                               const float* __restrict__ bhhB,
                               float* __restrict__ gates) {
    int bx  = blockIdx.x;
    int dir = bx >> 6;
    int t   = bx & 63;
    const float* Wih = dir ? WihB : WihF;
    const float* bih = dir ? bihB : bihF;
    const float* bhh = dir ? bhhB : bhhF;
    extern __shared__ float xs[];    // 8 * din
    int tid = threadIdx.x;
    for (int i = tid; i < 8 * din; i += 256) {
        int b = i / din, e = i % din;
        xs[i] = xmode ? x[((size_t)t * 8 + b) * din + e]
                      : x[((size_t)b * 64 + t) * din + e];
    }
    __syncthreads();
    float accb[8];
    float bias = bih[tid] + bhh[tid];
    #pragma unroll
    for (int b = 0; b < 8; b++) accb[b] = bias;
    const float* wrow = Wih + (size_t)tid * din;
    for (int e = 0; e < din; e += 4) {
        float4 w = *(const float4*)(wrow + e);
        #pragma unroll
        for (int b = 0; b < 8; b++) {
            const float* xr = xs + b * din + e;
            accb[b] += w.x * xr[0] + w.y * xr[1] + w.z * xr[2] + w.w * xr[3];
        }
    }
    int hh = tid & 63, g = tid >> 6;
    float* outp = gates + ((((size_t)dir * 64 + t) * 64 + hh) * 4 + g) * 8;
    #pragma unroll
    for (int b = 0; b < 8; b++) outp[b] = accb[b];
}

// ---------------------------------------------------------------------------
// Kernel 4: LSTM recurrence via MFMA. 1 block/dir, 256 threads (4 waves).
// Wave w owns gate cols g*64 + [16w,16w+16). Whh bf16 B-frags in registers.
// h double-buffered in swizzled LDS (bf16); 1 barrier/step.
// ---------------------------------------------------------------------------
__global__ __launch_bounds__(256) void lstm_rec_kernel(
    const float* __restrict__ gates,    // (2,64,64,4,8)
    const float* __restrict__ WhhF, const float* __restrict__ WhhB, // (256,64)
    float* __restrict__ hout)           // (64,8,128)
{
    int dir = blockIdx.x;
    const float* Whh = dir ? WhhB : WhhF;
    const float* gin = gates + (size_t)dir * 64 * 64 * 4 * 8;

    __shared__ unsigned short h16[2][16 * 64];

    int tid  = threadIdx.x;
    int lane = tid & 63;
    int w    = tid >> 6;
    int l15  = lane & 15;
    int q    = lane >> 4;
    int hh   = 16 * w + l15;

    // Whh B-fragments: Bf[g][kh], B[k][col] = Whh[col][k], col = g*64+hh
    bf16x8 Bf[4][2];
    #pragma unroll
    for (int g = 0; g < 4; g++)
        #pragma unroll
        for (int kh = 0; kh < 2; kh++) {
            const float* wp = Whh + (size_t)(g * 64 + hh) * 64 + kh * 32 + q * 8;
            float4 f0 = *(const float4*)wp;
            float4 f1 = *(const float4*)(wp + 4);
            bf16x8 r;
            r[0] = (__bf16)f0.x; r[1] = (__bf16)f0.y;
            r[2] = (__bf16)f0.z; r[3] = (__bf16)f0.w;
            r[4] = (__bf16)f1.x; r[5] = (__bf16)f1.y;
            r[6] = (__bf16)f1.z; r[7] = (__bf16)f1.w;
            Bf[g][kh] = r;
        }

    for (int i = tid; i < 2 * 16 * 64; i += 256)
        ((unsigned short*)h16)[i] = 0;
    float cst[4] = {0.f, 0.f, 0.f, 0.f};
    __syncthreads();

    // gin prefetch for step 0
    int t0 = dir ? 63 : 0;
    const float* gp = gin + (size_t)(t0 * 64 + hh) * 32 + 4 * (q & 1);
    f32x4 gv0 = *(const f32x4*)(gp);
    f32x4 gv1 = *(const f32x4*)(gp + 8);
    f32x4 gv2 = *(const f32x4*)(gp + 16);
    f32x4 gv3 = *(const f32x4*)(gp + 24);

    for (int s = 0; s < 64; ++s) {
        int t = dir ? 63 - s : s;
        const unsigned short* hb = h16[s & 1];
        int slot0 = q ^ (l15 & 7);
        int slot1 = (4 + q) ^ (l15 & 7);
        bf16x8 a0 = *(const bf16x8*)&hb[l15 * 64 + slot0 * 8];
        bf16x8 a1 = *(const bf16x8*)&hb[l15 * 64 + slot1 * 8];

        f32x4 zero = (f32x4){0.f, 0.f, 0.f, 0.f};
        f32x4 acc[4];
        #pragma unroll
        for (int g = 0; g < 4; g++) {
            acc[g] = __builtin_amdgcn_mfma_f32_16x16x32_bf16(a0, Bf[g][0], zero, 0, 0, 0);
            acc[g] = __builtin_amdgcn_mfma_f32_16x16x32_bf16(a1, Bf[g][1], acc[g], 0, 0, 0);
        }

        // prefetch gin for s+1
        int sn = (s + 1 < 64) ? s + 1 : 63;
        int t2 = dir ? 63 - sn : sn;
        const float* gp2 = gin + (size_t)(t2 * 64 + hh) * 32 + 4 * (q & 1);
        f32x4 n0 = *(const f32x4*)(gp2);
        f32x4 n1 = *(const f32x4*)(gp2 + 8);
        f32x4 n2 = *(const f32x4*)(gp2 + 16);
        f32x4 n3 = *(const f32x4*)(gp2 + 24);

        if (q < 2) {
            unsigned short* hw = h16[(s + 1) & 1];
            #pragma unroll
            for (int r = 0; r < 4; r++) {
                int b = 4 * q + r;
                float gi = acc[0][r] + gv0[r];
                float gf = acc[1][r] + gv1[r];
                float gg = acc[2][r] + gv2[r];
                float go = acc[3][r] + gv3[r];
                float cn = sigf(gf) * cst[r] + sigf(gi) * tanhff(gg);
                float hv = sigf(go) * tanhff(cn);
                cst[r] = cn;
                int slot = (hh >> 3) ^ (b & 7);
                hw[b * 64 + slot * 8 + (hh & 7)] = (unsigned short)f2bf(hv);
                hout[((size_t)t * 8 + b) * 128 + dir * 64 + hh] = hv;
            }
        }
        __syncthreads();
        gv0 = n0; gv1 = n1; gv2 = n2; gv3 = n3;
    }
}

// ---------------------------------------------------------------------------
// Kernel 5: feats (linear) + CRF forward scan + gold score, single block
// ---------------------------------------------------------------------------
__global__ __launch_bounds__(512) void crf_kernel(
    const float* __restrict__ h1,       // (64,8,128)
    const float* __restrict__ lin_w,    // (5,128)
    const float* __restrict__ lin_b,    // (5)
    const float* __restrict__ mask,     // (64,8)
    const int* __restrict__ tags,       // (64,8)
    const float* __restrict__ trans,    // (5,5)
    float* __restrict__ out) {
    __shared__ float feats[64][8][5];
    __shared__ float fwd_s[8], gold_s[8];
    __shared__ float tr[25], trE[5], lb[5];
    int tid = threadIdx.x;
    if (tid < 25) tr[tid] = trans[tid];
    if (tid < 5) { trE[tid] = trans[4 * 5 + tid]; lb[tid] = lin_b[tid]; }
    __syncthreads();

    for (int o = tid; o < 64 * 8 * 5; o += 512) {
        int i = o % 5; int b = (o / 5) & 7; int t = o / 40;
        const float* h = h1 + ((size_t)t * 8 + b) * 128;
        const float* w = lin_w + i * 128;
        float d = 0.f;
        for (int e = 0; e < 128; e++) d += h[e] * w[e];
        float m = mask[t * 8 + b];
        feats[t][b][i] = (m * d + lb[i]) * m;
    }
    __syncthreads();

    if (tid < 40) {    // wave 0, lane = b*5+i
        int b = tid / 5, i = tid % 5;
        float alpha = (i == 0) ? 0.f : NEG_VAL;    // SOS = 0
        float trow[5];
        #pragma unroll
        for (int j2 = 0; j2 < 5; j2++) trow[j2] = tr[i * 5 + j2];
        for (int t = 0; t < 64; t++) {
            float s0, s1, s2, s3, s4;
            s0 = __shfl(alpha, b * 5 + 0, 64) + trow[0];
            s1 = __shfl(alpha, b * 5 + 1, 64) + trow[1];
            s2 = __shfl(alpha, b * 5 + 2, 64) + trow[2];
            s3 = __shfl(alpha, b * 5 + 3, 64) + trow[3];
            s4 = __shfl(alpha, b * 5 + 4, 64) + trow[4];
            float mx = fmaxf(fmaxf(fmaxf(s0, s1), fmaxf(s2, s3)), s4);
            float sum = expf(s0 - mx) + expf(s1 - mx) + expf(s2 - mx) +
                        expf(s3 - mx) + expf(s4 - mx);
            float lse = mx + logf(sum) + feats[t][b][i];
            float mt = mask[t * 8 + b];
            alpha = mt * lse + (1.f - mt) * alpha;
        }
        float v = alpha + trE[i];
        float m0 = __shfl(v, b * 5 + 0, 64);
        float m1 = __shfl(v, b * 5 + 1, 64);
        float m2 = __shfl(v, b * 5 + 2, 64);
        float m3 = __shfl(v, b * 5 + 3, 64);
        float m4 = __shfl(v, b * 5 + 4, 64);
        float mx = fmaxf(fmaxf(fmaxf(m0, m1), fmaxf(m2, m3)), m4);
        float sum = expf(m0 - mx) + expf(m1 - mx) + expf(m2 - mx) +
                    expf(m3 - mx) + expf(m4 - mx);
        if (i == 0) fwd_s[b] = mx + logf(sum);
    }
    if (tid < 8) {
        int b = tid;
        float g = 0.f, lenf = 0.f;
        int prev = 0;   // SOS
        for (int t = 0; t < 64; t++) {
            int tg = tags[t * 8 + b];
            float mt = mask[t * 8 + b];
            g += (feats[t][b][tg] + tr[tg * 5 + prev]) * mt;
            lenf += mt;
            prev = tg;
        }
        int len = (int)lenf;
        int last = (len == 0) ? 0 : tags[(len - 1) * 8 + b];
        g += trE[last];
        gold_s[b] = g;
    }
    __syncthreads();
    if (tid == 0) {
        float s = 0.f;
        for (int b = 0; b < 8; b++) s += fwd_s[b] - gold_s[b];
        out[0] = s;
    }
}

// ---------------------------------------------------------------------------
extern "C" void kernel_launch(void* const* d_in, const int* in_sizes, int n_in,
                              void* d_out, int out_size, void* d_ws, size_t ws_size,
                              hipStream_t stream) {
    const int*   ids   = (const int*)d_in[0];
    const int*   tags  = (const int*)d_in[1];
    const float* mask  = (const float*)d_in[2];
    const float* emb   = (const float*)d_in[4];
    const float* cw3   = (const float*)d_in[5];
    const float* cb3   = (const float*)d_in[6];
    const float* cw4   = (const float*)d_in[7];
    const float* cb4   = (const float*)d_in[8];
    const float* cw5   = (const float*)d_in[9];
    const float* cb5   = (const float*)d_in[10];
    const float* Wih0f = (const float*)d_in[11];
    const float* Whh0f = (const float*)d_in[12];
    const float* bih0f = (const float*)d_in[13];
    const float* bhh0f = (const float*)d_in[14];
    const float* Wih0b = (const float*)d_in[15];
    const float* Whh0b = (const float*)d_in[16];
    const float* bih0b = (const float*)d_in[17];
    const float* bhh0b = (const float*)d_in[18];
    const float* Wih1f = (const float*)d_in[19];
    const float* Whh1f = (const float*)d_in[20];
    const float* bih1f = (const float*)d_in[21];
    const float* bhh1f = (const float*)d_in[22];
    const float* Wih1b = (const float*)d_in[23];
    const float* Whh1b = (const float*)d_in[24];
    const float* bih1b = (const float*)d_in[25];
    const float* bhh1b = (const float*)d_in[26];
    const float* lin_w = (const float*)d_in[27];
    const float* lin_b = (const float*)d_in[28];
    const float* trans = (const float*)d_in[29];

    char* ws = (char*)d_ws;
    unsigned short* wbc = (unsigned short*)ws;                 // 4,718,592 B
    float* para  = (float*)(ws + 4718592);                     // 1,572,864 B
    float* gates = (float*)(ws + 4718592 + 1572864);           // 1,048,576 B
    float* h0    = (float*)(ws + 4718592 + 1572864 + 1048576); //   262,144 B
    float* h1    = (float*)(ws + 4718592 + 1572864 + 1048576 + 262144);

    hipLaunchKernelGGL(cast_w_kernel, dim3(1152), dim3(256), 0, stream,
                       cw3, cw4, cw5, wbc);
    hipLaunchKernelGGL(conv_pool_kernel, dim3(384), dim3(512), 0, stream,
                       ids, emb, wbc, cb3, cb4, cb5, para);
    hipLaunchKernelGGL(gemm_in_kernel, dim3(128), dim3(256), 8 * 768 * 4, stream,
                       para, 0, 768, Wih0f, bih0f, bhh0f, Wih0b, bih0b, bhh0b, gates);
    hipLaunchKernelGGL(lstm_rec_kernel, dim3(2), dim3(256), 0, stream,
                       gates, Whh0f, Whh0b, h0);
    hipLaunchKernelGGL(gemm_in_kernel, dim3(128), dim3(256), 8 * 128 * 4, stream,
                       h0, 1, 128, Wih1f, bih1f, bhh1f, Wih1b, bih1b, bhh1b, gates);
    hipLaunchKernelGGL(lstm_rec_kernel, dim3(2), dim3(256), 0, stream,
                       gates, Whh1f, Whh1b, h1);
    hipLaunchKernelGGL(crf_kernel, dim3(1), dim3(512), 0, stream,
                       h1, lin_w, lin_b, mask, tags, trans, (float*)d_out);
}

// Round 3
// 444.351 us; speedup vs baseline: 1.4128x; 1.1069x over previous
//
#include <hip/hip_runtime.h>
#include <cstdint>
#include <cstddef>

#define DEV __device__ __forceinline__

typedef __bf16 bf16x8 __attribute__((ext_vector_type(8)));
typedef float f32x4 __attribute__((ext_vector_type(4)));

#define NEG_VAL -10000.0f

DEV unsigned int f2bf(float f) {
    unsigned int u = __float_as_uint(f);
    return (u + 0x7FFFu + ((u >> 16) & 1u)) >> 16;   // RNE to bf16
}
DEV unsigned int pk2(float a, float b) { return f2bf(a) | (f2bf(b) << 16); }

DEV void gload_lds16(const void* g, void* l) {
    __builtin_amdgcn_global_load_lds(
        (const __attribute__((address_space(1))) void*)g,
        (__attribute__((address_space(3))) void*)l, 16, 0, 0);
}

DEV float sigf(float x)  { return __builtin_amdgcn_rcpf(1.f + __expf(-x)); }
DEV float tanhff(float x){ return 2.f * __builtin_amdgcn_rcpf(1.f + __expf(-2.f * x)) - 1.f; }

// ---------------------------------------------------------------------------
// Kernel 1: cast conv weights fp32 -> bf16, chunked+swizzled:
// wbc[plane p(12)][c(24)][col(256)][slot g'(4)][8 bf16], content granule
// g = g' ^ ((col>>1)&3)
// ---------------------------------------------------------------------------
__global__ void cast_w_kernel(const float* __restrict__ cw3,
                              const float* __restrict__ cw4,
                              const float* __restrict__ cw5,
                              unsigned short* __restrict__ wbc) {
    int tid = blockIdx.x * blockDim.x + threadIdx.x;
    if (tid >= 12 * 24 * 256 * 4) return;
    int gp  = tid & 3;
    int col = (tid >> 2) & 255;
    int c   = (tid >> 10) % 24;
    int p   = tid / (24 * 256 * 4);
    int g = gp ^ ((col >> 1) & 3);
    int sz, j; const float* W;
    if (p < 3)      { sz = 3; j = p;     W = cw3; }
    else if (p < 7) { sz = 4; j = p - 3; W = cw4; }
    else            { sz = 5; j = p - 7; W = cw5; }
    const float* src = W + ((size_t)col * sz + j) * 768 + c * 32 + g * 8;
    float4 a = *(const float4*)(src);
    float4 b = *(const float4*)(src + 4);
    uint4 pk = make_uint4(pk2(a.x, a.y), pk2(a.z, a.w), pk2(b.x, b.y), pk2(b.z, b.w));
    reinterpret_cast<uint4*>(wbc)[tid] = pk;
}

// ---------------------------------------------------------------------------
// Kernel 2: conv via MFMA, T3/T4-style pipeline: raw s_barrier + counted
// vmcnt, 3-deep B buffers (gload_lds), X dbuf, emb prefetch SZ steps ahead.
// Wait schedule (derived, uniform via dummy-clamped issue):
//   end-of-step: vmcnt(6) for j<=1, else vmcnt(2); +lgkmcnt(0) on j==SZ-1
//   e-pack wait: vmcnt(4)
// ---------------------------------------------------------------------------
template<int SZ>
DEV void conv_body(const int* __restrict__ ids,
                   const float* __restrict__ emb,
                   const unsigned short* __restrict__ wbc,
                   const float* __restrict__ cb,
                   float* __restrict__ para,
                   int n0, int szi, int pbase,
                   unsigned short* Xlds, unsigned short* Blds)
{
    int tid  = threadIdx.x;
    int lane = tid & 63;
    int wid  = tid >> 6;
    int mw   = wid >> 1;
    int nw   = wid & 1;
    int l15  = lane & 15;
    int q    = lane >> 4;

    int srow  = tid >> 1;
    int shalf = tid & 1;
    int sid   = ids[(n0 + (srow >> 6)) * 64 + (srow & 63)];
    const float* embrow = emb + (size_t)sid * 768 + shalf * 16;
    int skey = (srow >> 1) & 3;
    int xoff0 = srow * 32 + (((2 * shalf)     ^ skey) * 8);
    int xoff1 = srow * 32 + (((2 * shalf + 1) ^ skey) * 8);

    f32x4 acc[4][8];
    #pragma unroll
    for (int a = 0; a < 4; a++)
        #pragma unroll
        for (int t = 0; t < 8; t++) acc[a][t] = (f32x4){0.f, 0.f, 0.f, 0.f};

    float4 e0, e1, e2, e3;

    // ---- prologue: e(c=0) -> pack X[0]; issue B(0), B(1)
    {
        e0 = ((const float4*)embrow)[0];
        e1 = ((const float4*)embrow)[1];
        e2 = ((const float4*)embrow)[2];
        e3 = ((const float4*)embrow)[3];
        const unsigned short* b0 = wbc + (size_t)(pbase * 24 + 0) * 8192;
        gload_lds16(b0 + tid * 8,        Blds + tid * 8);
        gload_lds16(b0 + 4096 + tid * 8, Blds + 4096 + tid * 8);
        const unsigned short* b1 = wbc +
            (size_t)((SZ > 1 ? pbase + 1 : pbase) * 24 + 0) * 8192;
        gload_lds16(b1 + tid * 8,        Blds + 8192 + tid * 8);
        gload_lds16(b1 + 4096 + tid * 8, Blds + 8192 + 4096 + tid * 8);
        uint4 p0 = make_uint4(pk2(e0.x, e0.y), pk2(e0.z, e0.w),
                              pk2(e1.x, e1.y), pk2(e1.z, e1.w));
        uint4 p1 = make_uint4(pk2(e2.x, e2.y), pk2(e2.z, e2.w),
                              pk2(e3.x, e3.y), pk2(e3.z, e3.w));
        *(uint4*)&Xlds[xoff0] = p0;
        *(uint4*)&Xlds[xoff1] = p1;
        __builtin_amdgcn_sched_barrier(0);
        asm volatile("s_waitcnt vmcnt(2) lgkmcnt(0)" ::: "memory");
        __builtin_amdgcn_s_barrier();
        __builtin_amdgcn_sched_barrier(0);
    }

    int bsel = 0;
    for (int c = 0; c < 24; c++) {
        const unsigned short* Xb = Xlds + (c & 1) * 8192;
        unsigned short* Xw = Xlds + ((c + 1) & 1) * 8192;
        #pragma unroll
        for (int j = 0; j < SZ; j++) {
            // issue B(s+2) (dummy-clamped for uniform vmcnt accounting)
            {
                int jn2 = (j + 2 < SZ) ? (j + 2) : (j + 2 - SZ);
                int cn2 = (j + 2 < SZ) ? c : (c + 1);
                if (cn2 > 23) cn2 = 0;
                int bw = bsel + 2; if (bw >= 3) bw -= 3;
                const unsigned short* bs =
                    wbc + (size_t)((pbase + jn2) * 24 + cn2) * 8192;
                gload_lds16(bs + tid * 8,        Blds + bw * 8192 + tid * 8);
                gload_lds16(bs + 4096 + tid * 8, Blds + bw * 8192 + 4096 + tid * 8);
            }
            if (j == 0) {   // emb prefetch for chunk c+1 (dummy at c=23)
                int cE = c + 1; if (cE > 23) cE = 0;
                const float* sp = embrow + cE * 32;
                e0 = ((const float4*)sp)[0];
                e1 = ((const float4*)sp)[1];
                e2 = ((const float4*)sp)[2];
                e3 = ((const float4*)sp)[3];
            }

            const unsigned short* Bb = Blds + bsel * 8192;
            bf16x8 af[4];
            #pragma unroll
            for (int a = 0; a < 4; a++) {
                int pj = 16 * a + l15 + j; if (pj > 63) pj = 63;
                int xr = 64 * mw + pj;
                af[a] = *reinterpret_cast<const bf16x8*>(
                    &Xb[xr * 32 + ((q ^ ((xr >> 1) & 3)) * 8)]);
            }
            bf16x8 bfr[8];
            #pragma unroll
            for (int t = 0; t < 8; t++) {
                int col = 128 * nw + 16 * t + l15;
                bfr[t] = *reinterpret_cast<const bf16x8*>(
                    &Bb[col * 32 + ((q ^ ((col >> 1) & 3)) * 8)]);
            }
            #pragma unroll
            for (int a = 0; a < 4; a++)
                #pragma unroll
                for (int t = 0; t < 8; t++)
                    acc[a][t] = __builtin_amdgcn_mfma_f32_16x16x32_bf16(
                        af[a], bfr[t], acc[a][t], 0, 0, 0);

            if (j == SZ - 1) {   // pack e -> X[(c+1)&1]
                __builtin_amdgcn_sched_barrier(0);
                asm volatile("s_waitcnt vmcnt(4)" ::: "memory");
                uint4 p0 = make_uint4(pk2(e0.x, e0.y), pk2(e0.z, e0.w),
                                      pk2(e1.x, e1.y), pk2(e1.z, e1.w));
                uint4 p1 = make_uint4(pk2(e2.x, e2.y), pk2(e2.z, e2.w),
                                      pk2(e3.x, e3.y), pk2(e3.z, e3.w));
                *(uint4*)&Xw[xoff0] = p0;
                *(uint4*)&Xw[xoff1] = p1;
            }

            __builtin_amdgcn_sched_barrier(0);
            if (j <= 1)
                asm volatile("s_waitcnt vmcnt(6)" ::: "memory");
            else if (j == SZ - 1)
                asm volatile("s_waitcnt vmcnt(2) lgkmcnt(0)" ::: "memory");
            else
                asm volatile("s_waitcnt vmcnt(2)" ::: "memory");
            __builtin_amdgcn_s_barrier();
            __builtin_amdgcn_sched_barrier(0);
            bsel++; if (bsel >= 3) bsel = 0;
        }
    }
    asm volatile("s_waitcnt vmcnt(0)" ::: "memory");

    // epilogue: relu(acc+bias), mask invalid windows, max over positions
    int n = n0 + mw;
    int pmax = 64 - SZ;
    #pragma unroll
    for (int t = 0; t < 8; t++) {
        int colb = 128 * nw + 16 * t;
        float bias = cb[colb + l15];
        float m = 0.0f;
        #pragma unroll
        for (int a = 0; a < 4; a++) {
            #pragma unroll
            for (int r = 0; r < 4; r++) {
                int p = 16 * a + q * 4 + r;
                float v = acc[a][t][r] + bias;
                v = v > 0.f ? v : 0.f;
                if (p <= pmax) m = v > m ? v : m;
            }
        }
        m = fmaxf(m, __shfl_xor(m, 16));
        m = fmaxf(m, __shfl_xor(m, 32));
        if (lane < 16)
            para[(size_t)n * 768 + szi * 256 + colb + lane] = m;
    }
}

__global__ __launch_bounds__(512, 2) void conv_pool_kernel(
    const int* __restrict__ ids,
    const float* __restrict__ emb,
    const unsigned short* __restrict__ wbc,
    const float* __restrict__ cb3, const float* __restrict__ cb4,
    const float* __restrict__ cb5,
    float* __restrict__ para)
{
    __shared__ unsigned short Xlds[2][8192];
    __shared__ unsigned short Blds[3][8192];
    int bx  = blockIdx.x;
    int szi = bx % 3;
    int n0  = (bx / 3) * 4;
    if (szi == 0)
        conv_body<3>(ids, emb, wbc, cb3, para, n0, 0, 0, &Xlds[0][0], &Blds[0][0]);
    else if (szi == 1)
        conv_body<4>(ids, emb, wbc, cb4, para, n0, 1, 3, &Xlds[0][0], &Blds[0][0]);
    else
        conv_body<5>(ids, emb, wbc, cb5, para, n0, 2, 7, &Xlds[0][0], &Blds[0][0]);
}

// ---------------------------------------------------------------------------
// Kernel 3: LSTM input projection. Output layout: gates[dir][t][hh][g][b]
// ---------------------------------------------------------------------------
__global__ void gemm_in_kernel(const float* __restrict__ x, int xmode, int din,
                               const float* __restrict__ WihF,
                               const float* __restrict__ bihF,
                               const float* __restrict__ bhhF,
                               const float* __restrict__ WihB,
                               const float* __restrict__ bihB,
                               const float* __restrict__ bhhB,
                               float* __restrict__ gates) {
    int bx  = blockIdx.x;
    int dir = bx >> 6;
    int t   = bx & 63;
    const float* Wih = dir ? WihB : WihF;
    const float* bih = dir ? bihB : bihF;
    const float* bhh = dir ? bhhB : bhhF;
    extern __shared__ float xs[];    // 8 * din
    int tid = threadIdx.x;
    for (int i = tid; i < 8 * din; i += 256) {
        int b = i / din, e = i % din;
        xs[i] = xmode ? x[((size_t)t * 8 + b) * din + e]
                      : x[((size_t)b * 64 + t) * din + e];
    }
    __syncthreads();
    float accb[8];
    float bias = bih[tid] + bhh[tid];
    #pragma unroll
    for (int b = 0; b < 8; b++) accb[b] = bias;
    const float* wrow = Wih + (size_t)tid * din;
    for (int e = 0; e < din; e += 4) {
        float4 w = *(const float4*)(wrow + e);
        #pragma unroll
        for (int b = 0; b < 8; b++) {
            const float* xr = xs + b * din + e;
            accb[b] += w.x * xr[0] + w.y * xr[1] + w.z * xr[2] + w.w * xr[3];
        }
    }
    int hh = tid & 63, g = tid >> 6;
    float* outp = gates + ((((size_t)dir * 64 + t) * 64 + hh) * 4 + g) * 8;
    #pragma unroll
    for (int b = 0; b < 8; b++) outp[b] = accb[b];
}

// ---------------------------------------------------------------------------
// Kernel 4: LSTM recurrence via MFMA. 1 block/dir, 256 threads (4 waves).
// ---------------------------------------------------------------------------
__global__ __launch_bounds__(256) void lstm_rec_kernel(
    const float* __restrict__ gates,    // (2,64,64,4,8)
    const float* __restrict__ WhhF, const float* __restrict__ WhhB, // (256,64)
    float* __restrict__ hout)           // (64,8,128)
{
    int dir = blockIdx.x;
    const float* Whh = dir ? WhhB : WhhF;
    const float* gin = gates + (size_t)dir * 64 * 64 * 4 * 8;

    __shared__ unsigned short h16[2][16 * 64];

    int tid  = threadIdx.x;
    int lane = tid & 63;
    int w    = tid >> 6;
    int l15  = lane & 15;
    int q    = lane >> 4;
    int hh   = 16 * w + l15;

    bf16x8 Bf[4][2];
    #pragma unroll
    for (int g = 0; g < 4; g++)
        #pragma unroll
        for (int kh = 0; kh < 2; kh++) {
            const float* wp = Whh + (size_t)(g * 64 + hh) * 64 + kh * 32 + q * 8;
            float4 f0 = *(const float4*)wp;
            float4 f1 = *(const float4*)(wp + 4);
            bf16x8 r;
            r[0] = (__bf16)f0.x; r[1] = (__bf16)f0.y;
            r[2] = (__bf16)f0.z; r[3] = (__bf16)f0.w;
            r[4] = (__bf16)f1.x; r[5] = (__bf16)f1.y;
            r[6] = (__bf16)f1.z; r[7] = (__bf16)f1.w;
            Bf[g][kh] = r;
        }

    for (int i = tid; i < 2 * 16 * 64; i += 256)
        ((unsigned short*)h16)[i] = 0;
    float cst[4] = {0.f, 0.f, 0.f, 0.f};
    __syncthreads();

    int t0 = dir ? 63 : 0;
    const float* gp = gin + (size_t)(t0 * 64 + hh) * 32 + 4 * (q & 1);
    f32x4 gv0 = *(const f32x4*)(gp);
    f32x4 gv1 = *(const f32x4*)(gp + 8);
    f32x4 gv2 = *(const f32x4*)(gp + 16);
    f32x4 gv3 = *(const f32x4*)(gp + 24);

    for (int s = 0; s < 64; ++s) {
        int t = dir ? 63 - s : s;
        const unsigned short* hb = h16[s & 1];
        int slot0 = q ^ (l15 & 7);
        int slot1 = (4 + q) ^ (l15 & 7);
        bf16x8 a0 = *(const bf16x8*)&hb[l15 * 64 + slot0 * 8];
        bf16x8 a1 = *(const bf16x8*)&hb[l15 * 64 + slot1 * 8];

        f32x4 zero = (f32x4){0.f, 0.f, 0.f, 0.f};
        f32x4 acc[4];
        #pragma unroll
        for (int g = 0; g < 4; g++) {
            acc[g] = __builtin_amdgcn_mfma_f32_16x16x32_bf16(a0, Bf[g][0], zero, 0, 0, 0);
            acc[g] = __builtin_amdgcn_mfma_f32_16x16x32_bf16(a1, Bf[g][1], acc[g], 0, 0, 0);
        }

        int sn = (s + 1 < 64) ? s + 1 : 63;
        int t2 = dir ? 63 - sn : sn;
        const float* gp2 = gin + (size_t)(t2 * 64 + hh) * 32 + 4 * (q & 1);
        f32x4 n0 = *(const f32x4*)(gp2);
        f32x4 n1 = *(const f32x4*)(gp2 + 8);
        f32x4 n2 = *(const f32x4*)(gp2 + 16);
        f32x4 n3 = *(const f32x4*)(gp2 + 24);

        if (q < 2) {
            unsigned short* hw = h16[(s + 1) & 1];
            #pragma unroll
            for (int r = 0; r < 4; r++) {
                int b = 4 * q + r;
                float gi = acc[0][r] + gv0[r];
                float gf = acc[1][r] + gv1[r];
                float gg = acc[2][r] + gv2[r];
                float go = acc[3][r] + gv3[r];
                float cn = sigf(gf) * cst[r] + sigf(gi) * tanhff(gg);
                float hv = sigf(go) * tanhff(cn);
                cst[r] = cn;
                int slot = (hh >> 3) ^ (b & 7);
                hw[b * 64 + slot * 8 + (hh & 7)] = (unsigned short)f2bf(hv);
                hout[((size_t)t * 8 + b) * 128 + dir * 64 + hh] = hv;
            }
        }
        __syncthreads();
        gv0 = n0; gv1 = n1; gv2 = n2; gv3 = n3;
    }
}

// ---------------------------------------------------------------------------
// Kernel 5: feats + CRF scan + gold, single block, LDS-staged
// ---------------------------------------------------------------------------
__global__ __launch_bounds__(512) void crf_kernel(
    const float* __restrict__ h1,       // (64,8,128)
    const float* __restrict__ lin_w,    // (5,128)
    const float* __restrict__ lin_b,    // (5)
    const float* __restrict__ mask,     // (64,8)
    const int* __restrict__ tags,       // (64,8)
    const float* __restrict__ trans,    // (5,5)
    float* __restrict__ out) {
    __shared__ float feats[64][8][5];
    __shared__ float wl[5][128];
    __shared__ float msk[512];
    __shared__ int   tgs[512];
    __shared__ float fwd_s[8], gold_s[8];
    __shared__ float tr[25], trE[5], lb[5];
    int tid = threadIdx.x;
    if (tid < 25) tr[tid] = trans[tid];
    if (tid < 5) { trE[tid] = trans[20 + tid]; lb[tid] = lin_b[tid]; }
    msk[tid] = mask[tid];
    tgs[tid] = tags[tid];
    if (tid < 128) {
        #pragma unroll
        for (int i = 0; i < 5; i++) wl[i][tid] = lin_w[i * 128 + tid];
    }
    __syncthreads();

    // feats: one thread per (t,b) row, float4 loads, wl broadcast from LDS
    {
        const float4* h4 = (const float4*)(h1 + (size_t)tid * 128);
        float a0 = 0.f, a1 = 0.f, a2 = 0.f, a3 = 0.f, a4 = 0.f;
        for (int e4 = 0; e4 < 32; e4++) {
            float4 hv = h4[e4];
            int e = e4 * 4;
            a0 += hv.x * wl[0][e] + hv.y * wl[0][e+1] + hv.z * wl[0][e+2] + hv.w * wl[0][e+3];
            a1 += hv.x * wl[1][e] + hv.y * wl[1][e+1] + hv.z * wl[1][e+2] + hv.w * wl[1][e+3];
            a2 += hv.x * wl[2][e] + hv.y * wl[2][e+1] + hv.z * wl[2][e+2] + hv.w * wl[2][e+3];
            a3 += hv.x * wl[3][e] + hv.y * wl[3][e+1] + hv.z * wl[3][e+2] + hv.w * wl[3][e+3];
            a4 += hv.x * wl[4][e] + hv.y * wl[4][e+1] + hv.z * wl[4][e+2] + hv.w * wl[4][e+3];
        }
        float m = msk[tid];
        int t = tid >> 3, b = tid & 7;
        feats[t][b][0] = (m * a0 + lb[0]) * m;
        feats[t][b][1] = (m * a1 + lb[1]) * m;
        feats[t][b][2] = (m * a2 + lb[2]) * m;
        feats[t][b][3] = (m * a3 + lb[3]) * m;
        feats[t][b][4] = (m * a4 + lb[4]) * m;
    }
    __syncthreads();

    if (tid < 40) {    // wave 0, lane = b*5+i
        int b = tid / 5, i = tid % 5;
        float alpha = (i == 0) ? 0.f : NEG_VAL;
        float trow[5];
        #pragma unroll
        for (int j2 = 0; j2 < 5; j2++) trow[j2] = tr[i * 5 + j2];
        for (int t = 0; t < 64; t++) {
            float s0, s1, s2, s3, s4;
            s0 = __shfl(alpha, b * 5 + 0, 64) + trow[0];
            s1 = __shfl(alpha, b * 5 + 1, 64) + trow[1];
            s2 = __shfl(alpha, b * 5 + 2, 64) + trow[2];
            s3 = __shfl(alpha, b * 5 + 3, 64) + trow[3];
            s4 = __shfl(alpha, b * 5 + 4, 64) + trow[4];
            float mx = fmaxf(fmaxf(fmaxf(s0, s1), fmaxf(s2, s3)), s4);
            float sum = expf(s0 - mx) + expf(s1 - mx) + expf(s2 - mx) +
                        expf(s3 - mx) + expf(s4 - mx);
            float lse = mx + logf(sum) + feats[t][b][i];
            float mt = msk[t * 8 + b];
            alpha = mt * lse + (1.f - mt) * alpha;
        }
        float v = alpha + trE[i];
        float m0 = __shfl(v, b * 5 + 0, 64);
        float m1 = __shfl(v, b * 5 + 1, 64);
        float m2 = __shfl(v, b * 5 + 2, 64);
        float m3 = __shfl(v, b * 5 + 3, 64);
        float m4 = __shfl(v, b * 5 + 4, 64);
        float mx = fmaxf(fmaxf(fmaxf(m0, m1), fmaxf(m2, m3)), m4);
        float sum = expf(m0 - mx) + expf(m1 - mx) + expf(m2 - mx) +
                    expf(m3 - mx) + expf(m4 - mx);
        if (i == 0) fwd_s[b] = mx + logf(sum);
    }
    if (tid >= 64 && tid < 72) {
        int b = tid - 64;
        float g = 0.f, lenf = 0.f;
        int prev = 0;   // SOS
        for (int t = 0; t < 64; t++) {
            int tg = tgs[t * 8 + b];
            float mt = msk[t * 8 + b];
            g += (feats[t][b][tg] + tr[tg * 5 + prev]) * mt;
            lenf += mt;
            prev = tg;
        }
        int len = (int)lenf;
        int last = (len == 0) ? 0 : tgs[(len - 1) * 8 + b];
        g += trE[last];
        gold_s[b] = g;
    }
    __syncthreads();
    if (tid == 0) {
        float s = 0.f;
        for (int b = 0; b < 8; b++) s += fwd_s[b] - gold_s[b];
        out[0] = s;
    }
}

// ---------------------------------------------------------------------------
extern "C" void kernel_launch(void* const* d_in, const int* in_sizes, int n_in,
                              void* d_out, int out_size, void* d_ws, size_t ws_size,
                              hipStream_t stream) {
    const int*   ids   = (const int*)d_in[0];
    const int*   tags  = (const int*)d_in[1];
    const float* mask  = (const float*)d_in[2];
    const float* emb   = (const float*)d_in[4];
    const float* cw3   = (const float*)d_in[5];
    const float* cb3   = (const float*)d_in[6];
    const float* cw4   = (const float*)d_in[7];
    const float* cb4   = (const float*)d_in[8];
    const float* cw5   = (const float*)d_in[9];
    const float* cb5   = (const float*)d_in[10];
    const float* Wih0f = (const float*)d_in[11];
    const float* Whh0f = (const float*)d_in[12];
    const float* bih0f = (const float*)d_in[13];
    const float* bhh0f = (const float*)d_in[14];
    const float* Wih0b = (const float*)d_in[15];
    const float* Whh0b = (const float*)d_in[16];
    const float* bih0b = (const float*)d_in[17];
    const float* bhh0b = (const float*)d_in[18];
    const float* Wih1f = (const float*)d_in[19];
    const float* Whh1f = (const float*)d_in[20];
    const float* bih1f = (const float*)d_in[21];
    const float* bhh1f = (const float*)d_in[22];
    const float* Wih1b = (const float*)d_in[23];
    const float* Whh1b = (const float*)d_in[24];
    const float* bih1b = (const float*)d_in[25];
    const float* bhh1b = (const float*)d_in[26];
    const float* lin_w = (const float*)d_in[27];
    const float* lin_b = (const float*)d_in[28];
    const float* trans = (const float*)d_in[29];

    char* ws = (char*)d_ws;
    unsigned short* wbc = (unsigned short*)ws;                 // 4,718,592 B
    float* para  = (float*)(ws + 4718592);                     // 1,572,864 B
    float* gates = (float*)(ws + 4718592 + 1572864);           // 1,048,576 B
    float* h0    = (float*)(ws + 4718592 + 1572864 + 1048576); //   262,144 B
    float* h1    = (float*)(ws + 4718592 + 1572864 + 1048576 + 262144);

    hipLaunchKernelGGL(cast_w_kernel, dim3(1152), dim3(256), 0, stream,
                       cw3, cw4, cw5, wbc);
    hipLaunchKernelGGL(conv_pool_kernel, dim3(384), dim3(512), 0, stream,
                       ids, emb, wbc, cb3, cb4, cb5, para);
    hipLaunchKernelGGL(gemm_in_kernel, dim3(128), dim3(256), 8 * 768 * 4, stream,
                       para, 0, 768, Wih0f, bih0f, bhh0f, Wih0b, bih0b, bhh0b, gates);
    hipLaunchKernelGGL(lstm_rec_kernel, dim3(2), dim3(256), 0, stream,
                       gates, Whh0f, Whh0b, h0);
    hipLaunchKernelGGL(gemm_in_kernel, dim3(128), dim3(256), 8 * 128 * 4, stream,
                       h0, 1, 128, Wih1f, bih1f, bhh1f, Wih1b, bih1b, bhh1b, gates);
    hipLaunchKernelGGL(lstm_rec_kernel, dim3(2), dim3(256), 0, stream,
                       gates, Whh1f, Whh1b, h1);
    hipLaunchKernelGGL(crf_kernel, dim3(1), dim3(512), 0, stream,
                       h1, lin_w, lin_b, mask, tags, trans, (float*)d_out);
}

// Round 4
// 326.959 us; speedup vs baseline: 1.9201x; 1.3590x over previous
//
#include <hip/hip_runtime.h>
#include <cstdint>
#include <cstddef>

#define DEV __device__ __forceinline__

typedef __bf16 bf16x8 __attribute__((ext_vector_type(8)));
typedef float f32x4 __attribute__((ext_vector_type(4)));

#define NEG_VAL -10000.0f

DEV unsigned int f2bf(float f) {
    unsigned int u = __float_as_uint(f);
    return (u + 0x7FFFu + ((u >> 16) & 1u)) >> 16;   // RNE to bf16
}
DEV unsigned int pk2(float a, float b) { return f2bf(a) | (f2bf(b) << 16); }

DEV float sigf(float x)  { return __builtin_amdgcn_rcpf(1.f + __expf(-x)); }
DEV float tanhff(float x){ return 2.f * __builtin_amdgcn_rcpf(1.f + __expf(-2.f * x)) - 1.f; }

// ---------------------------------------------------------------------------
// Kernel 1: cast conv weights fp32 -> bf16, register-direct-load layout:
// tile(p,c) = 8192 u16; element (col,k) at u16 index
//   (col>>4)*512 + (k>>3)*128 + (col&15)*8 + (k&7)
// so a wave's bfr[t] load (lane = (k>>3)*16 + (col&15)) is one coalesced
// global_load_dwordx4 at tile + (nw*8+t)*512 + lane*8.
// ---------------------------------------------------------------------------
__global__ void cast_w_kernel(const float* __restrict__ cw3,
                              const float* __restrict__ cw4,
                              const float* __restrict__ cw5,
                              unsigned short* __restrict__ wbc) {
    int tid = blockIdx.x * blockDim.x + threadIdx.x;
    if (tid >= 12 * 24 * 256 * 4) return;
    int g   = tid & 3;           // k granule (k>>3)
    int col = (tid >> 2) & 255;
    int c   = (tid >> 10) % 24;
    int p   = tid / (24 * 256 * 4);
    int sz, j; const float* W;
    if (p < 3)      { sz = 3; j = p;     W = cw3; }
    else if (p < 7) { sz = 4; j = p - 3; W = cw4; }
    else            { sz = 5; j = p - 7; W = cw5; }
    const float* src = W + ((size_t)col * sz + j) * 768 + c * 32 + g * 8;
    float4 a = *(const float4*)(src);
    float4 b = *(const float4*)(src + 4);
    uint4 pk = make_uint4(pk2(a.x, a.y), pk2(a.z, a.w), pk2(b.x, b.y), pk2(b.z, b.w));
    size_t dst = (size_t)(p * 24 + c) * 1024 + (col >> 4) * 64 + g * 16 + (col & 15);
    reinterpret_cast<uint4*>(wbc)[dst] = pk;
}

// ---------------------------------------------------------------------------
// Kernel 2: conv via MFMA. B global->register (double-buffered, 1 step ahead),
// X (embeddings, bf16) in small dbuf LDS; ONE barrier per c-chunk.
// Block = 256 thr (4 waves), 2 sentences; wave tile 64 rows x 128 cols.
// ---------------------------------------------------------------------------
template<int SZ>
DEV void conv_body(const int* __restrict__ ids,
                   const float* __restrict__ emb,
                   const unsigned short* __restrict__ wbc,
                   const float* __restrict__ cb,
                   float* __restrict__ para,
                   int pair, int szi, int pbase,
                   unsigned short* Xlds)
{
    int tid  = threadIdx.x;
    int lane = tid & 63;
    int wid  = tid >> 6;        // 0..3
    int mw   = wid >> 1;        // sentence within pair
    int nw   = wid & 1;         // 128-col half
    int l15  = lane & 15;
    int q    = lane >> 4;
    int n0   = pair * 2;

    int srow  = tid >> 1;       // 0..127
    int shalf = tid & 1;
    int sid   = ids[(n0 + (srow >> 6)) * 64 + (srow & 63)];
    const float* embrow = emb + (size_t)sid * 768 + shalf * 16;
    int skey = (srow >> 1) & 3;
    int xo0 = srow * 32 + (((2 * shalf)     ^ skey) * 8);
    int xo1 = srow * 32 + (((2 * shalf + 1) ^ skey) * 8);

    f32x4 acc[4][8];
    #pragma unroll
    for (int a = 0; a < 4; a++)
        #pragma unroll
        for (int t = 0; t < 8; t++) acc[a][t] = (f32x4){0.f, 0.f, 0.f, 0.f};

    bf16x8 bfr[2][8];
    float4 e0, e1, e2, e3;

    // ---- prologue: X(c=0) -> buf0; issue B(j=0,c=0) -> bfr[0]
    {
        e0 = ((const float4*)embrow)[0];
        e1 = ((const float4*)embrow)[1];
        e2 = ((const float4*)embrow)[2];
        e3 = ((const float4*)embrow)[3];
        const unsigned short* bt =
            wbc + (size_t)(pbase * 24) * 8192 + nw * 4096 + lane * 8;
        #pragma unroll
        for (int t = 0; t < 8; t++)
            bfr[0][t] = *(const bf16x8*)(bt + t * 512);
        uint4 p0 = make_uint4(pk2(e0.x, e0.y), pk2(e0.z, e0.w),
                              pk2(e1.x, e1.y), pk2(e1.z, e1.w));
        uint4 p1 = make_uint4(pk2(e2.x, e2.y), pk2(e2.z, e2.w),
                              pk2(e3.x, e3.y), pk2(e3.z, e3.w));
        *(uint4*)&Xlds[xo0] = p0;
        *(uint4*)&Xlds[xo1] = p1;
        asm volatile("s_waitcnt lgkmcnt(0)" ::: "memory");
        __builtin_amdgcn_s_barrier();
    }

    for (int c2 = 0; c2 < 24; c2 += 2) {
        #pragma unroll
        for (int s2 = 0; s2 < 2 * SZ; ++s2) {
            const int half = (s2 < SZ) ? 0 : 1;
            const int j    = s2 - half * SZ;
            const int par  = s2 & 1;          // global step parity (c2 even)
            const int cc   = c2 + half;

            // issue B(next step) -> bfr[par^1] (clamped dummy at the very end)
            {
                int jn, cn;
                if (s2 + 1 < 2 * SZ) {
                    int hn = (s2 + 1 < SZ) ? 0 : 1;
                    jn = s2 + 1 - hn * SZ; cn = c2 + hn;
                } else { jn = 0; cn = c2 + 2; }
                if (cn > 23) cn = 0;
                const unsigned short* bt =
                    wbc + (size_t)((pbase + jn) * 24 + cn) * 8192 + nw * 4096 + lane * 8;
                #pragma unroll
                for (int t = 0; t < 8; t++)
                    bfr[par ^ 1][t] = *(const bf16x8*)(bt + t * 512);
            }
            // emb prefetch for chunk cc+1 (dummy-clamped)
            if (s2 == 0 || s2 == SZ) {
                int cE = cc + 1; if (cE > 23) cE = 0;
                const float* sp = embrow + cE * 32;
                e0 = ((const float4*)sp)[0];
                e1 = ((const float4*)sp)[1];
                e2 = ((const float4*)sp)[2];
                e3 = ((const float4*)sp)[3];
            }

            // A frags from LDS buffer (cc&1)
            const unsigned short* Xb = Xlds + (cc & 1) * 4096;
            bf16x8 af[4];
            #pragma unroll
            for (int a = 0; a < 4; a++) {
                int pj = 16 * a + l15 + j; if (pj > 63) pj = 63;
                int xr = 64 * mw + pj;
                af[a] = *(const bf16x8*)(&Xb[xr * 32 + ((q ^ ((xr >> 1) & 3)) * 8)]);
            }

            __builtin_amdgcn_s_setprio(1);
            #pragma unroll
            for (int a = 0; a < 4; a++)
                #pragma unroll
                for (int t = 0; t < 8; t++)
                    acc[a][t] = __builtin_amdgcn_mfma_f32_16x16x32_bf16(
                        af[a], bfr[par][t], acc[a][t], 0, 0, 0);
            __builtin_amdgcn_s_setprio(0);

            if (j == SZ - 1) {   // chunk end: pack X(cc+1) -> buffer (cc+1)&1
                unsigned short* Xw = Xlds + ((cc + 1) & 1) * 4096;
                uint4 p0 = make_uint4(pk2(e0.x, e0.y), pk2(e0.z, e0.w),
                                      pk2(e1.x, e1.y), pk2(e1.z, e1.w));
                uint4 p1 = make_uint4(pk2(e2.x, e2.y), pk2(e2.z, e2.w),
                                      pk2(e3.x, e3.y), pk2(e3.z, e3.w));
                *(uint4*)&Xw[xo0] = p0;
                *(uint4*)&Xw[xo1] = p1;
                asm volatile("s_waitcnt lgkmcnt(0)" ::: "memory");
                __builtin_amdgcn_s_barrier();
            }
        }
    }

    // epilogue: relu(acc+bias), mask invalid windows, max over positions
    int n = n0 + mw;
    int pmax = 64 - SZ;
    #pragma unroll
    for (int t = 0; t < 8; t++) {
        int colb = 128 * nw + 16 * t;
        float bias = cb[colb + l15];
        float m = 0.0f;
        #pragma unroll
        for (int a = 0; a < 4; a++) {
            #pragma unroll
            for (int r = 0; r < 4; r++) {
                int p = 16 * a + q * 4 + r;
                float v = acc[a][t][r] + bias;
                v = v > 0.f ? v : 0.f;
                if (p <= pmax) m = v > m ? v : m;
            }
        }
        m = fmaxf(m, __shfl_xor(m, 16));
        m = fmaxf(m, __shfl_xor(m, 32));
        if (lane < 16)
            para[(size_t)n * 768 + szi * 256 + colb + lane] = m;
    }
}

__global__ __launch_bounds__(256, 2) void conv_pool_kernel(
    const int* __restrict__ ids,
    const float* __restrict__ emb,
    const unsigned short* __restrict__ wbc,
    const float* __restrict__ cb3, const float* __restrict__ cb4,
    const float* __restrict__ cb5,
    float* __restrict__ para)
{
    __shared__ unsigned short Xlds[2][4096];   // 128 rows x 32 e, dbuf
    int bx   = blockIdx.x;
    int szi  = bx >> 8;        // szi-major: co-resident blocks share B tiles
    int pair = bx & 255;
    if (szi == 0)
        conv_body<3>(ids, emb, wbc, cb3, para, pair, 0, 0, &Xlds[0][0]);
    else if (szi == 1)
        conv_body<4>(ids, emb, wbc, cb4, para, pair, 1, 3, &Xlds[0][0]);
    else
        conv_body<5>(ids, emb, wbc, cb5, para, pair, 2, 7, &Xlds[0][0]);
}

// ---------------------------------------------------------------------------
// Kernel 3: LSTM input projection. Output layout: gates[dir][t][hh][g][b]
// ---------------------------------------------------------------------------
__global__ void gemm_in_kernel(const float* __restrict__ x, int xmode, int din,
                               const float* __restrict__ WihF,
                               const float* __restrict__ bihF,
                               const float* __restrict__ bhhF,
                               const float* __restrict__ WihB,
                               const float* __restrict__ bihB,
                               const float* __restrict__ bhhB,
                               float* __restrict__ gates) {
    int bx  = blockIdx.x;
    int dir = bx >> 6;
    int t   = bx & 63;
    const float* Wih = dir ? WihB : WihF;
    const float* bih = dir ? bihB : bihF;
    const float* bhh = dir ? bhhB : bhhF;
    extern __shared__ float xs[];    // 8 * din
    int tid = threadIdx.x;
    for (int i = tid; i < 8 * din; i += 256) {
        int b = i / din, e = i % din;
        xs[i] = xmode ? x[((size_t)t * 8 + b) * din + e]
                      : x[((size_t)b * 64 + t) * din + e];
    }
    __syncthreads();
    float accb[8];
    float bias = bih[tid] + bhh[tid];
    #pragma unroll
    for (int b = 0; b < 8; b++) accb[b] = bias;
    const float* wrow = Wih + (size_t)tid * din;
    for (int e = 0; e < din; e += 4) {
        float4 w = *(const float4*)(wrow + e);
        #pragma unroll
        for (int b = 0; b < 8; b++) {
            const float* xr = xs + b * din + e;
            accb[b] += w.x * xr[0] + w.y * xr[1] + w.z * xr[2] + w.w * xr[3];
        }
    }
    int hh = tid & 63, g = tid >> 6;
    float* outp = gates + ((((size_t)dir * 64 + t) * 64 + hh) * 4 + g) * 8;
    #pragma unroll
    for (int b = 0; b < 8; b++) outp[b] = accb[b];
}

// ---------------------------------------------------------------------------
// Kernel 4: LSTM recurrence via MFMA. 1 block/dir, 256 threads (4 waves).
// ---------------------------------------------------------------------------
__global__ __launch_bounds__(256) void lstm_rec_kernel(
    const float* __restrict__ gates,    // (2,64,64,4,8)
    const float* __restrict__ WhhF, const float* __restrict__ WhhB, // (256,64)
    float* __restrict__ hout)           // (64,8,128)
{
    int dir = blockIdx.x;
    const float* Whh = dir ? WhhB : WhhF;
    const float* gin = gates + (size_t)dir * 64 * 64 * 4 * 8;

    __shared__ unsigned short h16[2][16 * 64];

    int tid  = threadIdx.x;
    int lane = tid & 63;
    int w    = tid >> 6;
    int l15  = lane & 15;
    int q    = lane >> 4;
    int hh   = 16 * w + l15;

    bf16x8 Bf[4][2];
    #pragma unroll
    for (int g = 0; g < 4; g++)
        #pragma unroll
        for (int kh = 0; kh < 2; kh++) {
            const float* wp = Whh + (size_t)(g * 64 + hh) * 64 + kh * 32 + q * 8;
            float4 f0 = *(const float4*)wp;
            float4 f1 = *(const float4*)(wp + 4);
            bf16x8 r;
            r[0] = (__bf16)f0.x; r[1] = (__bf16)f0.y;
            r[2] = (__bf16)f0.z; r[3] = (__bf16)f0.w;
            r[4] = (__bf16)f1.x; r[5] = (__bf16)f1.y;
            r[6] = (__bf16)f1.z; r[7] = (__bf16)f1.w;
            Bf[g][kh] = r;
        }

    for (int i = tid; i < 2 * 16 * 64; i += 256)
        ((unsigned short*)h16)[i] = 0;
    float cst[4] = {0.f, 0.f, 0.f, 0.f};
    __syncthreads();

    int t0 = dir ? 63 : 0;
    const float* gp = gin + (size_t)(t0 * 64 + hh) * 32 + 4 * (q & 1);
    f32x4 gv0 = *(const f32x4*)(gp);
    f32x4 gv1 = *(const f32x4*)(gp + 8);
    f32x4 gv2 = *(const f32x4*)(gp + 16);
    f32x4 gv3 = *(const f32x4*)(gp + 24);

    for (int s = 0; s < 64; ++s) {
        int t = dir ? 63 - s : s;
        const unsigned short* hb = h16[s & 1];
        int slot0 = q ^ (l15 & 7);
        int slot1 = (4 + q) ^ (l15 & 7);
        bf16x8 a0 = *(const bf16x8*)&hb[l15 * 64 + slot0 * 8];
        bf16x8 a1 = *(const bf16x8*)&hb[l15 * 64 + slot1 * 8];

        f32x4 zero = (f32x4){0.f, 0.f, 0.f, 0.f};
        f32x4 acc[4];
        #pragma unroll
        for (int g = 0; g < 4; g++) {
            acc[g] = __builtin_amdgcn_mfma_f32_16x16x32_bf16(a0, Bf[g][0], zero, 0, 0, 0);
            acc[g] = __builtin_amdgcn_mfma_f32_16x16x32_bf16(a1, Bf[g][1], acc[g], 0, 0, 0);
        }

        int sn = (s + 1 < 64) ? s + 1 : 63;
        int t2 = dir ? 63 - sn : sn;
        const float* gp2 = gin + (size_t)(t2 * 64 + hh) * 32 + 4 * (q & 1);
        f32x4 n0 = *(const f32x4*)(gp2);
        f32x4 n1 = *(const f32x4*)(gp2 + 8);
        f32x4 n2 = *(const f32x4*)(gp2 + 16);
        f32x4 n3 = *(const f32x4*)(gp2 + 24);

        if (q < 2) {
            unsigned short* hw = h16[(s + 1) & 1];
            #pragma unroll
            for (int r = 0; r < 4; r++) {
                int b = 4 * q + r;
                float gi = acc[0][r] + gv0[r];
                float gf = acc[1][r] + gv1[r];
                float gg = acc[2][r] + gv2[r];
                float go = acc[3][r] + gv3[r];
                float cn = sigf(gf) * cst[r] + sigf(gi) * tanhff(gg);
                float hv = sigf(go) * tanhff(cn);
                cst[r] = cn;
                int slot = (hh >> 3) ^ (b & 7);
                hw[b * 64 + slot * 8 + (hh & 7)] = (unsigned short)f2bf(hv);
                hout[((size_t)t * 8 + b) * 128 + dir * 64 + hh] = hv;
            }
        }
        __syncthreads();
        gv0 = n0; gv1 = n1; gv2 = n2; gv3 = n3;
    }
}

// ---------------------------------------------------------------------------
// Kernel 5: feats + CRF scan + gold, single block, LDS-staged
// ---------------------------------------------------------------------------
__global__ __launch_bounds__(512) void crf_kernel(
    const float* __restrict__ h1,       // (64,8,128)
    const float* __restrict__ lin_w,    // (5,128)
    const float* __restrict__ lin_b,    // (5)
    const float* __restrict__ mask,     // (64,8)
    const int* __restrict__ tags,       // (64,8)
    const float* __restrict__ trans,    // (5,5)
    float* __restrict__ out) {
    __shared__ float feats[64][8][5];
    __shared__ float wl[5][128];
    __shared__ float msk[512];
    __shared__ int   tgs[512];
    __shared__ float fwd_s[8], gold_s[8];
    __shared__ float tr[25], trE[5], lb[5];
    int tid = threadIdx.x;
    if (tid < 25) tr[tid] = trans[tid];
    if (tid < 5) { trE[tid] = trans[20 + tid]; lb[tid] = lin_b[tid]; }
    msk[tid] = mask[tid];
    tgs[tid] = tags[tid];
    if (tid < 128) {
        #pragma unroll
        for (int i = 0; i < 5; i++) wl[i][tid] = lin_w[i * 128 + tid];
    }
    __syncthreads();

    {
        const float4* h4 = (const float4*)(h1 + (size_t)tid * 128);
        float a0 = 0.f, a1 = 0.f, a2 = 0.f, a3 = 0.f, a4 = 0.f;
        for (int e4 = 0; e4 < 32; e4++) {
            float4 hv = h4[e4];
            int e = e4 * 4;
            a0 += hv.x * wl[0][e] + hv.y * wl[0][e+1] + hv.z * wl[0][e+2] + hv.w * wl[0][e+3];
            a1 += hv.x * wl[1][e] + hv.y * wl[1][e+1] + hv.z * wl[1][e+2] + hv.w * wl[1][e+3];
            a2 += hv.x * wl[2][e] + hv.y * wl[2][e+1] + hv.z * wl[2][e+2] + hv.w * wl[2][e+3];
            a3 += hv.x * wl[3][e] + hv.y * wl[3][e+1] + hv.z * wl[3][e+2] + hv.w * wl[3][e+3];
            a4 += hv.x * wl[4][e] + hv.y * wl[4][e+1] + hv.z * wl[4][e+2] + hv.w * wl[4][e+3];
        }
        float m = msk[tid];
        int t = tid >> 3, b = tid & 7;
        feats[t][b][0] = (m * a0 + lb[0]) * m;
        feats[t][b][1] = (m * a1 + lb[1]) * m;
        feats[t][b][2] = (m * a2 + lb[2]) * m;
        feats[t][b][3] = (m * a3 + lb[3]) * m;
        feats[t][b][4] = (m * a4 + lb[4]) * m;
    }
    __syncthreads();

    if (tid < 40) {    // wave 0, lane = b*5+i
        int b = tid / 5, i = tid % 5;
        float alpha = (i == 0) ? 0.f : NEG_VAL;
        float trow[5];
        #pragma unroll
        for (int j2 = 0; j2 < 5; j2++) trow[j2] = tr[i * 5 + j2];
        for (int t = 0; t < 64; t++) {
            float s0, s1, s2, s3, s4;
            s0 = __shfl(alpha, b * 5 + 0, 64) + trow[0];
            s1 = __shfl(alpha, b * 5 + 1, 64) + trow[1];
            s2 = __shfl(alpha, b * 5 + 2, 64) + trow[2];
            s3 = __shfl(alpha, b * 5 + 3, 64) + trow[3];
            s4 = __shfl(alpha, b * 5 + 4, 64) + trow[4];
            float mx = fmaxf(fmaxf(fmaxf(s0, s1), fmaxf(s2, s3)), s4);
            float sum = expf(s0 - mx) + expf(s1 - mx) + expf(s2 - mx) +
                        expf(s3 - mx) + expf(s4 - mx);
            float lse = mx + logf(sum) + feats[t][b][i];
            float mt = msk[t * 8 + b];
            alpha = mt * lse + (1.f - mt) * alpha;
        }
        float v = alpha + trE[i];
        float m0 = __shfl(v, b * 5 + 0, 64);
        float m1 = __shfl(v, b * 5 + 1, 64);
        float m2 = __shfl(v, b * 5 + 2, 64);
        float m3 = __shfl(v, b * 5 + 3, 64);
        float m4 = __shfl(v, b * 5 + 4, 64);
        float mx = fmaxf(fmaxf(fmaxf(m0, m1), fmaxf(m2, m3)), m4);
        float sum = expf(m0 - mx) + expf(m1 - mx) + expf(m2 - mx) +
                    expf(m3 - mx) + expf(m4 - mx);
        if (i == 0) fwd_s[b] = mx + logf(sum);
    }
    if (tid >= 64 && tid < 72) {
        int b = tid - 64;
        float g = 0.f, lenf = 0.f;
        int prev = 0;   // SOS
        for (int t = 0; t < 64; t++) {
            int tg = tgs[t * 8 + b];
            float mt = msk[t * 8 + b];
            g += (feats[t][b][tg] + tr[tg * 5 + prev]) * mt;
            lenf += mt;
            prev = tg;
        }
        int len = (int)lenf;
        int last = (len == 0) ? 0 : tgs[(len - 1) * 8 + b];
        g += trE[last];
        gold_s[b] = g;
    }
    __syncthreads();
    if (tid == 0) {
        float s = 0.f;
        for (int b = 0; b < 8; b++) s += fwd_s[b] - gold_s[b];
        out[0] = s;
    }
}

// ---------------------------------------------------------------------------
extern "C" void kernel_launch(void* const* d_in, const int* in_sizes, int n_in,
                              void* d_out, int out_size, void* d_ws, size_t ws_size,
                              hipStream_t stream) {
    const int*   ids   = (const int*)d_in[0];
    const int*   tags  = (const int*)d_in[1];
    const float* mask  = (const float*)d_in[2];
    const float* emb   = (const float*)d_in[4];
    const float* cw3   = (const float*)d_in[5];
    const float* cb3   = (const float*)d_in[6];
    const float* cw4   = (const float*)d_in[7];
    const float* cb4   = (const float*)d_in[8];
    const float* cw5   = (const float*)d_in[9];
    const float* cb5   = (const float*)d_in[10];
    const float* Wih0f = (const float*)d_in[11];
    const float* Whh0f = (const float*)d_in[12];
    const float* bih0f = (const float*)d_in[13];
    const float* bhh0f = (const float*)d_in[14];
    const float* Wih0b = (const float*)d_in[15];
    const float* Whh0b = (const float*)d_in[16];
    const float* bih0b = (const float*)d_in[17];
    const float* bhh0b = (const float*)d_in[18];
    const float* Wih1f = (const float*)d_in[19];
    const float* Whh1f = (const float*)d_in[20];
    const float* bih1f = (const float*)d_in[21];
    const float* bhh1f = (const float*)d_in[22];
    const float* Wih1b = (const float*)d_in[23];
    const float* Whh1b = (const float*)d_in[24];
    const float* bih1b = (const float*)d_in[25];
    const float* bhh1b = (const float*)d_in[26];
    const float* lin_w = (const float*)d_in[27];
    const float* lin_b = (const float*)d_in[28];
    const float* trans = (const float*)d_in[29];

    char* ws = (char*)d_ws;
    unsigned short* wbc = (unsigned short*)ws;                 // 4,718,592 B
    float* para  = (float*)(ws + 4718592);                     // 1,572,864 B
    float* gates = (float*)(ws + 4718592 + 1572864);           // 1,048,576 B
    float* h0    = (float*)(ws + 4718592 + 1572864 + 1048576); //   262,144 B
    float* h1    = (float*)(ws + 4718592 + 1572864 + 1048576 + 262144);

    hipLaunchKernelGGL(cast_w_kernel, dim3(1152), dim3(256), 0, stream,
                       cw3, cw4, cw5, wbc);
    hipLaunchKernelGGL(conv_pool_kernel, dim3(768), dim3(256), 0, stream,
                       ids, emb, wbc, cb3, cb4, cb5, para);
    hipLaunchKernelGGL(gemm_in_kernel, dim3(128), dim3(256), 8 * 768 * 4, stream,
                       para, 0, 768, Wih0f, bih0f, bhh0f, Wih0b, bih0b, bhh0b, gates);
    hipLaunchKernelGGL(lstm_rec_kernel, dim3(2), dim3(256), 0, stream,
                       gates, Whh0f, Whh0b, h0);
    hipLaunchKernelGGL(gemm_in_kernel, dim3(128), dim3(256), 8 * 128 * 4, stream,
                       h0, 1, 128, Wih1f, bih1f, bhh1f, Wih1b, bih1b, bhh1b, gates);
    hipLaunchKernelGGL(lstm_rec_kernel, dim3(2), dim3(256), 0, stream,
                       gates, Whh1f, Whh1b, h1);
    hipLaunchKernelGGL(crf_kernel, dim3(1), dim3(512), 0, stream,
                       h1, lin_w, lin_b, mask, tags, trans, (float*)d_out);
}

// Round 5
// 287.541 us; speedup vs baseline: 2.1833x; 1.1371x over previous
//
#include <hip/hip_runtime.h>
#include <cstdint>
#include <cstddef>

#define DEV __device__ __forceinline__

typedef __bf16 bf16x8 __attribute__((ext_vector_type(8)));
typedef float f32x4 __attribute__((ext_vector_type(4)));

#define NEG_VAL -10000.0f

DEV unsigned int f2bf(float f) {
    unsigned int u = __float_as_uint(f);
    return (u + 0x7FFFu + ((u >> 16) & 1u)) >> 16;   // RNE to bf16
}
DEV unsigned int pk2(float a, float b) { return f2bf(a) | (f2bf(b) << 16); }

DEV float sigf(float x)  { return __builtin_amdgcn_rcpf(1.f + __expf(-x)); }
DEV float tanhff(float x){ return 2.f * __builtin_amdgcn_rcpf(1.f + __expf(-2.f * x)) - 1.f; }

// ---------------------------------------------------------------------------
// Kernel 1: cast ALL weights fp32 -> bf16 register-direct tile layout.
// Tile = 256 cols x 32 k of bf16 (8192 u16 = 1024 uint4);
// element (col,k) at uint4 index (col>>4)*64 + (k>>3)*16 + (col&15).
//  - wbc:   conv weights, tile (p,c): p=plane (12), c=k-chunk (24)
//  - wih0c: Wih layer0, tile (dir*24 + kc)
//  - wih1c: Wih layer1, tile (dir*4 + kc)
// ---------------------------------------------------------------------------
__global__ void cast_all_kernel(const float* __restrict__ cw3,
                                const float* __restrict__ cw4,
                                const float* __restrict__ cw5,
                                const float* __restrict__ Wih0f,
                                const float* __restrict__ Wih0b,
                                const float* __restrict__ Wih1f,
                                const float* __restrict__ Wih1b,
                                unsigned short* __restrict__ wbc,
                                unsigned short* __restrict__ wih0c,
                                unsigned short* __restrict__ wih1c) {
    int tid = blockIdx.x * blockDim.x + threadIdx.x;
    const float* src;
    uint4* dstp;
    if (tid < 294912) {                       // conv: 12*24*256*4
        int g   = tid & 3;
        int col = (tid >> 2) & 255;
        int c   = (tid >> 10) % 24;
        int p   = tid / (24 * 256 * 4);
        int sz, j; const float* W;
        if (p < 3)      { sz = 3; j = p;     W = cw3; }
        else if (p < 7) { sz = 4; j = p - 3; W = cw4; }
        else            { sz = 5; j = p - 7; W = cw5; }
        src = W + ((size_t)col * sz + j) * 768 + c * 32 + g * 8;
        dstp = reinterpret_cast<uint4*>(wbc) +
               ((size_t)(p * 24 + c) * 1024 + (col >> 4) * 64 + g * 16 + (col & 15));
    } else if (tid < 294912 + 49152) {        // Wih0: 2*24*256*4
        int u   = tid - 294912;
        int g   = u & 3;
        int col = (u >> 2) & 255;
        int kc  = (u >> 10) % 24;
        int dir = u / (24 * 256 * 4);
        const float* W = dir ? Wih0b : Wih0f;
        src = W + (size_t)col * 768 + kc * 32 + g * 8;
        dstp = reinterpret_cast<uint4*>(wih0c) +
               ((size_t)(dir * 24 + kc) * 1024 + (col >> 4) * 64 + g * 16 + (col & 15));
    } else if (tid < 294912 + 49152 + 8192) { // Wih1: 2*4*256*4
        int u   = tid - 294912 - 49152;
        int g   = u & 3;
        int col = (u >> 2) & 255;
        int kc  = (u >> 10) % 4;
        int dir = u / (4 * 256 * 4);
        const float* W = dir ? Wih1b : Wih1f;
        src = W + (size_t)col * 128 + kc * 32 + g * 8;
        dstp = reinterpret_cast<uint4*>(wih1c) +
               ((size_t)(dir * 4 + kc) * 1024 + (col >> 4) * 64 + g * 16 + (col & 15));
    } else return;
    float4 a = *(const float4*)(src);
    float4 b = *(const float4*)(src + 4);
    *dstp = make_uint4(pk2(a.x, a.y), pk2(a.z, a.w), pk2(b.x, b.y), pk2(b.z, b.w));
}

// ---------------------------------------------------------------------------
// Kernel 2: conv via MFMA. B global->register (dbuf, SGPR-hoisted tile index,
// immediate offsets), X in dbuf LDS with PRECOMPUTED ds addresses (c2-pair
// unroll -> compile-time buffer parity). One barrier per c-chunk.
// Output: para_bf bf16, rows t*8+b.
// ---------------------------------------------------------------------------
template<int SZ>
DEV void conv_body(const int* __restrict__ ids,
                   const float* __restrict__ emb,
                   const unsigned short* __restrict__ wbc,
                   const float* __restrict__ cb,
                   unsigned short* __restrict__ para_bf,
                   int pair, int szi, int pbase,
                   unsigned short* Xlds)
{
    int tid  = threadIdx.x;
    int lane = tid & 63;
    int wid  = tid >> 6;
    int mw   = wid >> 1;
    int nw   = wid & 1;
    int l15  = lane & 15;
    int q    = lane >> 4;
    int n0   = pair * 2;

    int srow  = tid >> 1;
    int shalf = tid & 1;
    int sid   = ids[(n0 + (srow >> 6)) * 64 + (srow & 63)];
    const float* embrow = emb + (size_t)sid * 768 + shalf * 16;
    int skey = (srow >> 1) & 3;
    int xo0 = srow * 32 + (((2 * shalf)     ^ skey) * 8);
    int xo1 = srow * 32 + (((2 * shalf + 1) ^ skey) * 8);

    // precomputed A ds-read offsets (u16 units) within one X buffer
    int vXa[SZ][4];
    #pragma unroll
    for (int j = 0; j < SZ; j++)
        #pragma unroll
        for (int a = 0; a < 4; a++) {
            int pj = 16 * a + l15 + j; if (pj > 63) pj = 63;
            int xr = 64 * mw + pj;
            vXa[j][a] = xr * 32 + ((q ^ ((xr >> 1) & 3)) * 8);
        }
    int vlaneB = nw * 4096 + lane * 8;     // u16 units

    f32x4 acc[4][8];
    #pragma unroll
    for (int a = 0; a < 4; a++)
        #pragma unroll
        for (int t = 0; t < 8; t++) acc[a][t] = (f32x4){0.f, 0.f, 0.f, 0.f};

    bf16x8 bfr[2][8];
    float4 e0, e1, e2, e3;

    // prologue: e(c=0), bfr[0] <= tile pbase*24, pack X buf0, barrier
    {
        e0 = ((const float4*)embrow)[0];
        e1 = ((const float4*)embrow)[1];
        e2 = ((const float4*)embrow)[2];
        e3 = ((const float4*)embrow)[3];
        const unsigned short* bt = wbc + (size_t)(pbase * 24) * 8192 + vlaneB;
        #pragma unroll
        for (int t = 0; t < 8; t++)
            bfr[0][t] = *(const bf16x8*)(bt + t * 512);
        uint4 p0 = make_uint4(pk2(e0.x, e0.y), pk2(e0.z, e0.w),
                              pk2(e1.x, e1.y), pk2(e1.z, e1.w));
        uint4 p1 = make_uint4(pk2(e2.x, e2.y), pk2(e2.z, e2.w),
                              pk2(e3.x, e3.y), pk2(e3.z, e3.w));
        *(uint4*)&Xlds[xo0] = p0;
        *(uint4*)&Xlds[xo1] = p1;
        asm volatile("s_waitcnt lgkmcnt(0)" ::: "memory");
        __builtin_amdgcn_s_barrier();
    }

    int cbase = pbase * 24;    // uniform tile base, advances by 2 per c2
    for (int c2 = 0; c2 < 24; c2 += 2, cbase += 2) {
        #pragma unroll
        for (int s2 = 0; s2 < 2 * SZ; ++s2) {
            const int half = (s2 < SZ) ? 0 : 1;
            const int j    = s2 - half * SZ;
            const int par  = s2 & 1;
            // prefetch B(s2+1): compile-time tile offset from cbase
            {
                const int sP = s2 + 1;
                const int offP = (sP < SZ) ? sP * 24
                               : (sP < 2 * SZ ? (sP - SZ) * 24 + 1 : 2);
                const unsigned short* bt =
                    wbc + (size_t)(cbase + offP) * 8192 + vlaneB;
                #pragma unroll
                for (int t = 0; t < 8; t++)
                    bfr[par ^ 1][t] = *(const bf16x8*)(bt + t * 512);
            }
            if (s2 == 0 || s2 == SZ) {      // emb prefetch for next chunk
                int cE = half ? c2 + 2 : c2 + 1; if (cE > 23) cE = 0;
                const float* sp = embrow + cE * 32;
                e0 = ((const float4*)sp)[0];
                e1 = ((const float4*)sp)[1];
                e2 = ((const float4*)sp)[2];
                e3 = ((const float4*)sp)[3];
            }

            const unsigned short* Xb = Xlds + half * 4096;
            bf16x8 af[4];
            #pragma unroll
            for (int a = 0; a < 4; a++)
                af[a] = *(const bf16x8*)(&Xb[vXa[j][a]]);

            __builtin_amdgcn_s_setprio(1);
            #pragma unroll
            for (int a = 0; a < 4; a++)
                #pragma unroll
                for (int t = 0; t < 8; t++)
                    acc[a][t] = __builtin_amdgcn_mfma_f32_16x16x32_bf16(
                        af[a], bfr[par][t], acc[a][t], 0, 0, 0);
            __builtin_amdgcn_s_setprio(0);

            if (j == SZ - 1) {   // pack X(next chunk) into other buffer
                unsigned short* Xw = Xlds + (half ^ 1) * 4096;
                uint4 p0 = make_uint4(pk2(e0.x, e0.y), pk2(e0.z, e0.w),
                                      pk2(e1.x, e1.y), pk2(e1.z, e1.w));
                uint4 p1 = make_uint4(pk2(e2.x, e2.y), pk2(e2.z, e2.w),
                                      pk2(e3.x, e3.y), pk2(e3.z, e3.w));
                *(uint4*)&Xw[xo0] = p0;
                *(uint4*)&Xw[xo1] = p1;
                asm volatile("s_waitcnt lgkmcnt(0)" ::: "memory");
                __builtin_amdgcn_s_barrier();
            }
        }
    }

    // epilogue: relu(acc+bias), mask, maxpool, store bf16 to row t*8+b
    int n = n0 + mw;
    int row = (n & 63) * 8 + (n >> 6);     // t*8 + b
    int pmax = 64 - SZ;
    #pragma unroll
    for (int t = 0; t < 8; t++) {
        int colb = 128 * nw + 16 * t;
        float bias = cb[colb + l15];
        float m = 0.0f;
        #pragma unroll
        for (int a = 0; a < 4; a++) {
            #pragma unroll
            for (int r = 0; r < 4; r++) {
                int p = 16 * a + q * 4 + r;
                float v = acc[a][t][r] + bias;
                v = v > 0.f ? v : 0.f;
                if (p <= pmax) m = v > m ? v : m;
            }
        }
        m = fmaxf(m, __shfl_xor(m, 16));
        m = fmaxf(m, __shfl_xor(m, 32));
        if (lane < 16)
            para_bf[(size_t)row * 768 + szi * 256 + colb + lane] =
                (unsigned short)f2bf(m);
    }
}

__global__ __launch_bounds__(256, 2) void conv_pool_kernel(
    const int* __restrict__ ids,
    const float* __restrict__ emb,
    const unsigned short* __restrict__ wbc,
    const float* __restrict__ cb3, const float* __restrict__ cb4,
    const float* __restrict__ cb5,
    unsigned short* __restrict__ para_bf)
{
    __shared__ unsigned short Xlds[2][4096];
    int bx   = blockIdx.x;
    int szi  = bx >> 8;
    int pair = bx & 255;
    if (szi == 0)
        conv_body<3>(ids, emb, wbc, cb3, para_bf, pair, 0, 0, &Xlds[0][0]);
    else if (szi == 1)
        conv_body<4>(ids, emb, wbc, cb4, para_bf, pair, 1, 3, &Xlds[0][0]);
    else
        conv_body<5>(ids, emb, wbc, cb5, para_bf, pair, 2, 7, &Xlds[0][0]);
}

// ---------------------------------------------------------------------------
// Kernel 3: LSTM input projection via MFMA, no LDS, no barriers.
// x (bf16, rows m = t*8+b, stride din) register-direct A; W tiles register-
// direct B; out gates[dir][nn=g*64+hh][m] fp32 col-major (f32x4 stores).
// Grid: 16 blocks = dir*8 + rowg*2 + colg; block 256 thr (4 waves).
// ---------------------------------------------------------------------------
template<int KC>
__global__ __launch_bounds__(256) void gemm_in_kernel(
    const unsigned short* __restrict__ xbf,   // [512][KC*32]
    const unsigned short* __restrict__ wihc,  // [2*KC] tiles
    const float* __restrict__ bihF, const float* __restrict__ bhhF,
    const float* __restrict__ bihB, const float* __restrict__ bhhB,
    float* __restrict__ gates)                // [2][256][512]
{
    const int din = KC * 32;
    int bx   = blockIdx.x;
    int dir  = bx >> 3;
    int rowg = (bx >> 1) & 3;
    int colg = bx & 1;
    int tid  = threadIdx.x;
    int lane = tid & 63;
    int wid  = tid >> 6;
    int mw   = wid >> 1;
    int nw   = wid & 1;
    int l15  = lane & 15;
    int q    = lane >> 4;

    const float* bih = dir ? bihB : bihF;
    const float* bhh = dir ? bhhB : bhhF;
    const unsigned short* wt = wihc + (size_t)dir * KC * 8192;

    const unsigned short* arow[4];
    #pragma unroll
    for (int a = 0; a < 4; a++)
        arow[a] = xbf + (size_t)(rowg * 128 + mw * 64 + a * 16 + l15) * din + q * 8;
    const unsigned short* bbase = wt + (colg * 8 + nw * 4) * 512 + lane * 8;

    f32x4 acc[4][4];
    #pragma unroll
    for (int a = 0; a < 4; a++)
        #pragma unroll
        for (int t = 0; t < 4; t++) acc[a][t] = (f32x4){0.f, 0.f, 0.f, 0.f};

    bf16x8 afb[2][4], bfb[2][4];
    #pragma unroll
    for (int a = 0; a < 4; a++) afb[0][a] = *(const bf16x8*)(arow[a]);
    #pragma unroll
    for (int t = 0; t < 4; t++) bfb[0][t] = *(const bf16x8*)(bbase + t * 512);

    #pragma unroll 2
    for (int kc = 0; kc < KC; ++kc) {
        const int p = kc & 1;
        int kn = (kc + 1 < KC) ? kc + 1 : kc;
        #pragma unroll
        for (int a = 0; a < 4; a++)
            afb[p ^ 1][a] = *(const bf16x8*)(arow[a] + kn * 32);
        #pragma unroll
        for (int t = 0; t < 4; t++)
            bfb[p ^ 1][t] = *(const bf16x8*)(bbase + (size_t)kn * 8192 + t * 512);
        __builtin_amdgcn_s_setprio(1);
        #pragma unroll
        for (int a = 0; a < 4; a++)
            #pragma unroll
            for (int t = 0; t < 4; t++)
                acc[a][t] = __builtin_amdgcn_mfma_f32_16x16x32_bf16(
                    afb[p][a], bfb[p][t], acc[a][t], 0, 0, 0);
        __builtin_amdgcn_s_setprio(0);
    }

    // epilogue: + (bih+bhh), coalesced f32x4 stores, m fastest
    #pragma unroll
    for (int t = 0; t < 4; t++) {
        int nn = colg * 128 + nw * 64 + t * 16 + l15;
        float bb = bih[nn] + bhh[nn];
        float* gp = gates + ((size_t)dir * 256 + nn) * 512 +
                    rowg * 128 + mw * 64 + q * 4;
        #pragma unroll
        for (int a = 0; a < 4; a++) {
            f32x4 v = acc[a][t];
            v[0] += bb; v[1] += bb; v[2] += bb; v[3] += bb;
            *(f32x4*)(gp + a * 16) = v;
        }
    }
}

// ---------------------------------------------------------------------------
// Kernel 4: LSTM recurrence via MFMA. 1 block/dir, 256 threads (4 waves).
// gin layout [dir][nn][m=t*8+b]. Writes fp32 houtF and bf16 houtB.
// ---------------------------------------------------------------------------
__global__ __launch_bounds__(256) void lstm_rec_kernel(
    const float* __restrict__ gates,    // (2,256,512)
    const float* __restrict__ WhhF, const float* __restrict__ WhhB, // (256,64)
    float* __restrict__ houtF,          // (64,8,128)
    unsigned short* __restrict__ houtB) // (64,8,128) bf16
{
    int dir = blockIdx.x;
    const float* Whh = dir ? WhhB : WhhF;
    const float* gin = gates + (size_t)dir * 256 * 512;

    __shared__ unsigned short h16[2][16 * 64];

    int tid  = threadIdx.x;
    int lane = tid & 63;
    int w    = tid >> 6;
    int l15  = lane & 15;
    int q    = lane >> 4;
    int hh   = 16 * w + l15;

    bf16x8 Bf[4][2];
    #pragma unroll
    for (int g = 0; g < 4; g++)
        #pragma unroll
        for (int kh = 0; kh < 2; kh++) {
            const float* wp = Whh + (size_t)(g * 64 + hh) * 64 + kh * 32 + q * 8;
            float4 f0 = *(const float4*)wp;
            float4 f1 = *(const float4*)(wp + 4);
            bf16x8 r;
            r[0] = (__bf16)f0.x; r[1] = (__bf16)f0.y;
            r[2] = (__bf16)f0.z; r[3] = (__bf16)f0.w;
            r[4] = (__bf16)f1.x; r[5] = (__bf16)f1.y;
            r[6] = (__bf16)f1.z; r[7] = (__bf16)f1.w;
            Bf[g][kh] = r;
        }

    const float* pg0 = gin + ((size_t)(0 * 64 + hh)) * 512 + 4 * (q & 1);
    const float* pg1 = gin + ((size_t)(1 * 64 + hh)) * 512 + 4 * (q & 1);
    const float* pg2 = gin + ((size_t)(2 * 64 + hh)) * 512 + 4 * (q & 1);
    const float* pg3 = gin + ((size_t)(3 * 64 + hh)) * 512 + 4 * (q & 1);

    for (int i = tid; i < 2 * 16 * 64; i += 256)
        ((unsigned short*)h16)[i] = 0;
    float cst[4] = {0.f, 0.f, 0.f, 0.f};
    __syncthreads();

    int t0 = dir ? 63 : 0;
    f32x4 gv0 = *(const f32x4*)(pg0 + t0 * 8);
    f32x4 gv1 = *(const f32x4*)(pg1 + t0 * 8);
    f32x4 gv2 = *(const f32x4*)(pg2 + t0 * 8);
    f32x4 gv3 = *(const f32x4*)(pg3 + t0 * 8);

    for (int s = 0; s < 64; ++s) {
        int t = dir ? 63 - s : s;
        const unsigned short* hb = h16[s & 1];
        int slot0 = q ^ (l15 & 7);
        int slot1 = (4 + q) ^ (l15 & 7);
        bf16x8 a0 = *(const bf16x8*)&hb[l15 * 64 + slot0 * 8];
        bf16x8 a1 = *(const bf16x8*)&hb[l15 * 64 + slot1 * 8];

        f32x4 zero = (f32x4){0.f, 0.f, 0.f, 0.f};
        f32x4 acc[4];
        #pragma unroll
        for (int g = 0; g < 4; g++) {
            acc[g] = __builtin_amdgcn_mfma_f32_16x16x32_bf16(a0, Bf[g][0], zero, 0, 0, 0);
            acc[g] = __builtin_amdgcn_mfma_f32_16x16x32_bf16(a1, Bf[g][1], acc[g], 0, 0, 0);
        }

        int sn = (s + 1 < 64) ? s + 1 : 63;
        int t2 = dir ? 63 - sn : sn;
        f32x4 n0 = *(const f32x4*)(pg0 + t2 * 8);
        f32x4 n1 = *(const f32x4*)(pg1 + t2 * 8);
        f32x4 n2 = *(const f32x4*)(pg2 + t2 * 8);
        f32x4 n3 = *(const f32x4*)(pg3 + t2 * 8);

        if (q < 2) {
            unsigned short* hw = h16[(s + 1) & 1];
            #pragma unroll
            for (int r = 0; r < 4; r++) {
                int b = 4 * q + r;
                float gi = acc[0][r] + gv0[r];
                float gf = acc[1][r] + gv1[r];
                float gg = acc[2][r] + gv2[r];
                float go = acc[3][r] + gv3[r];
                float cn = sigf(gf) * cst[r] + sigf(gi) * tanhff(gg);
                float hv = sigf(go) * tanhff(cn);
                cst[r] = cn;
                int slot = (hh >> 3) ^ (b & 7);
                hw[b * 64 + slot * 8 + (hh & 7)] = (unsigned short)f2bf(hv);
                size_t oi = ((size_t)t * 8 + b) * 128 + dir * 64 + hh;
                houtF[oi] = hv;
                houtB[oi] = (unsigned short)f2bf(hv);
            }
        }
        __syncthreads();
        gv0 = n0; gv1 = n1; gv2 = n2; gv3 = n3;
    }
}

// ---------------------------------------------------------------------------
// Kernel 5: feats + CRF scan + gold, single block, LDS-staged
// ---------------------------------------------------------------------------
__global__ __launch_bounds__(512) void crf_kernel(
    const float* __restrict__ h1,       // (64,8,128)
    const float* __restrict__ lin_w,    // (5,128)
    const float* __restrict__ lin_b,    // (5)
    const float* __restrict__ mask,     // (64,8)
    const int* __restrict__ tags,       // (64,8)
    const float* __restrict__ trans,    // (5,5)
    float* __restrict__ out) {
    __shared__ float feats[64][8][5];
    __shared__ float wl[5][128];
    __shared__ float msk[512];
    __shared__ int   tgs[512];
    __shared__ float fwd_s[8], gold_s[8];
    __shared__ float tr[25], trE[5], lb[5];
    int tid = threadIdx.x;
    if (tid < 25) tr[tid] = trans[tid];
    if (tid < 5) { trE[tid] = trans[20 + tid]; lb[tid] = lin_b[tid]; }
    msk[tid] = mask[tid];
    tgs[tid] = tags[tid];
    if (tid < 128) {
        #pragma unroll
        for (int i = 0; i < 5; i++) wl[i][tid] = lin_w[i * 128 + tid];
    }
    __syncthreads();

    {
        const float4* h4 = (const float4*)(h1 + (size_t)tid * 128);
        float a0 = 0.f, a1 = 0.f, a2 = 0.f, a3 = 0.f, a4 = 0.f;
        for (int e4 = 0; e4 < 32; e4++) {
            float4 hv = h4[e4];
            int e = e4 * 4;
            a0 += hv.x * wl[0][e] + hv.y * wl[0][e+1] + hv.z * wl[0][e+2] + hv.w * wl[0][e+3];
            a1 += hv.x * wl[1][e] + hv.y * wl[1][e+1] + hv.z * wl[1][e+2] + hv.w * wl[1][e+3];
            a2 += hv.x * wl[2][e] + hv.y * wl[2][e+1] + hv.z * wl[2][e+2] + hv.w * wl[2][e+3];
            a3 += hv.x * wl[3][e] + hv.y * wl[3][e+1] + hv.z * wl[3][e+2] + hv.w * wl[3][e+3];
            a4 += hv.x * wl[4][e] + hv.y * wl[4][e+1] + hv.z * wl[4][e+2] + hv.w * wl[4][e+3];
        }
        float m = msk[tid];
        int t = tid >> 3, b = tid & 7;
        feats[t][b][0] = (m * a0 + lb[0]) * m;
        feats[t][b][1] = (m * a1 + lb[1]) * m;
        feats[t][b][2] = (m * a2 + lb[2]) * m;
        feats[t][b][3] = (m * a3 + lb[3]) * m;
        feats[t][b][4] = (m * a4 + lb[4]) * m;
    }
    __syncthreads();

    if (tid < 40) {    // wave 0, lane = b*5+i
        int b = tid / 5, i = tid % 5;
        float alpha = (i == 0) ? 0.f : NEG_VAL;
        float trow[5];
        #pragma unroll
        for (int j2 = 0; j2 < 5; j2++) trow[j2] = tr[i * 5 + j2];
        for (int t = 0; t < 64; t++) {
            float s0, s1, s2, s3, s4;
            s0 = __shfl(alpha, b * 5 + 0, 64) + trow[0];
            s1 = __shfl(alpha, b * 5 + 1, 64) + trow[1];
            s2 = __shfl(alpha, b * 5 + 2, 64) + trow[2];
            s3 = __shfl(alpha, b * 5 + 3, 64) + trow[3];
            s4 = __shfl(alpha, b * 5 + 4, 64) + trow[4];
            float mx = fmaxf(fmaxf(fmaxf(s0, s1), fmaxf(s2, s3)), s4);
            float sum = expf(s0 - mx) + expf(s1 - mx) + expf(s2 - mx) +
                        expf(s3 - mx) + expf(s4 - mx);
            float lse = mx + logf(sum) + feats[t][b][i];
            float mt = msk[t * 8 + b];
            alpha = mt * lse + (1.f - mt) * alpha;
        }
        float v = alpha + trE[i];
        float m0 = __shfl(v, b * 5 + 0, 64);
        float m1 = __shfl(v, b * 5 + 1, 64);
        float m2 = __shfl(v, b * 5 + 2, 64);
        float m3 = __shfl(v, b * 5 + 3, 64);
        float m4 = __shfl(v, b * 5 + 4, 64);
        float mx = fmaxf(fmaxf(fmaxf(m0, m1), fmaxf(m2, m3)), m4);
        float sum = expf(m0 - mx) + expf(m1 - mx) + expf(m2 - mx) +
                    expf(m3 - mx) + expf(m4 - mx);
        if (i == 0) fwd_s[b] = mx + logf(sum);
    }
    if (tid >= 64 && tid < 72) {
        int b = tid - 64;
        float g = 0.f, lenf = 0.f;
        int prev = 0;   // SOS
        for (int t = 0; t < 64; t++) {
            int tg = tgs[t * 8 + b];
            float mt = msk[t * 8 + b];
            g += (feats[t][b][tg] + tr[tg * 5 + prev]) * mt;
            lenf += mt;
            prev = tg;
        }
        int len = (int)lenf;
        int last = (len == 0) ? 0 : tgs[(len - 1) * 8 + b];
        g += trE[last];
        gold_s[b] = g;
    }
    __syncthreads();
    if (tid == 0) {
        float s = 0.f;
        for (int b = 0; b < 8; b++) s += fwd_s[b] - gold_s[b];
        out[0] = s;
    }
}

// ---------------------------------------------------------------------------
extern "C" void kernel_launch(void* const* d_in, const int* in_sizes, int n_in,
                              void* d_out, int out_size, void* d_ws, size_t ws_size,
                              hipStream_t stream) {
    const int*   ids   = (const int*)d_in[0];
    const int*   tags  = (const int*)d_in[1];
    const float* mask  = (const float*)d_in[2];
    const float* emb   = (const float*)d_in[4];
    const float* cw3   = (const float*)d_in[5];
    const float* cb3   = (const float*)d_in[6];
    const float* cw4   = (const float*)d_in[7];
    const float* cb4   = (const float*)d_in[8];
    const float* cw5   = (const float*)d_in[9];
    const float* cb5   = (const float*)d_in[10];
    const float* Wih0f = (const float*)d_in[11];
    const float* Whh0f = (const float*)d_in[12];
    const float* bih0f = (const float*)d_in[13];
    const float* bhh0f = (const float*)d_in[14];
    const float* Wih0b = (const float*)d_in[15];
    const float* Whh0b = (const float*)d_in[16];
    const float* bih0b = (const float*)d_in[17];
    const float* bhh0b = (const float*)d_in[18];
    const float* Wih1f = (const float*)d_in[19];
    const float* Whh1f = (const float*)d_in[20];
    const float* bih1f = (const float*)d_in[21];
    const float* bhh1f = (const float*)d_in[22];
    const float* Wih1b = (const float*)d_in[23];
    const float* Whh1b = (const float*)d_in[24];
    const float* bih1b = (const float*)d_in[25];
    const float* bhh1b = (const float*)d_in[26];
    const float* lin_w = (const float*)d_in[27];
    const float* lin_b = (const float*)d_in[28];
    const float* trans = (const float*)d_in[29];

    // workspace layout (with lifetime-safe aliasing):
    //  0        wbc      4,718,592
    //  4718592  wih0c      786,432   (reused as h1f after gemm0)
    //  5505024  wih1c      131,072
    //  5636096  para_bf    786,432   (reused as h0_bf after gemm0,
    //                                 then as h1_bf scratch after gemm1)
    //  6422528  gates    1,048,576
    //  7471104  h0f        262,144   (dead output, layer0 fp32)
    char* ws = (char*)d_ws;
    unsigned short* wbc     = (unsigned short*)ws;
    unsigned short* wih0c   = (unsigned short*)(ws + 4718592);
    unsigned short* wih1c   = (unsigned short*)(ws + 5505024);
    unsigned short* para_bf = (unsigned short*)(ws + 5636096);
    float*          gates   = (float*)(ws + 6422528);
    float*          h0f     = (float*)(ws + 7471104);
    unsigned short* h0_bf   = (unsigned short*)(ws + 5636096);
    float*          h1f     = (float*)(ws + 4718592);
    unsigned short* h1_bf   = (unsigned short*)(ws + 5636096);

    hipLaunchKernelGGL(cast_all_kernel, dim3(1376), dim3(256), 0, stream,
                       cw3, cw4, cw5, Wih0f, Wih0b, Wih1f, Wih1b,
                       wbc, wih0c, wih1c);
    hipLaunchKernelGGL(conv_pool_kernel, dim3(768), dim3(256), 0, stream,
                       ids, emb, wbc, cb3, cb4, cb5, para_bf);
    hipLaunchKernelGGL((gemm_in_kernel<24>), dim3(16), dim3(256), 0, stream,
                       para_bf, wih0c, bih0f, bhh0f, bih0b, bhh0b, gates);
    hipLaunchKernelGGL(lstm_rec_kernel, dim3(2), dim3(256), 0, stream,
                       gates, Whh0f, Whh0b, h0f, h0_bf);
    hipLaunchKernelGGL((gemm_in_kernel<4>), dim3(16), dim3(256), 0, stream,
                       h0_bf, wih1c, bih1f, bhh1f, bih1b, bhh1b, gates);
    hipLaunchKernelGGL(lstm_rec_kernel, dim3(2), dim3(256), 0, stream,
                       gates, Whh1f, Whh1b, h1f, h1_bf);
    hipLaunchKernelGGL(crf_kernel, dim3(1), dim3(512), 0, stream,
                       h1f, lin_w, lin_b, mask, tags, trans, (float*)d_out);
}

// Round 6
// 283.017 us; speedup vs baseline: 2.2182x; 1.0160x over previous
//
#include <hip/hip_runtime.h>
#include <cstdint>
#include <cstddef>

#define DEV __device__ __forceinline__

typedef __bf16 bf16x8 __attribute__((ext_vector_type(8)));
typedef float f32x4 __attribute__((ext_vector_type(4)));

#define NEG_VAL -10000.0f

DEV unsigned int f2bf(float f) {
    unsigned int u = __float_as_uint(f);
    return (u + 0x7FFFu + ((u >> 16) & 1u)) >> 16;   // RNE to bf16
}
DEV unsigned int pk2(float a, float b) { return f2bf(a) | (f2bf(b) << 16); }

DEV float sigf(float x)  { return __builtin_amdgcn_rcpf(1.f + __expf(-x)); }
DEV float tanhff(float x){ return 2.f * __builtin_amdgcn_rcpf(1.f + __expf(-2.f * x)) - 1.f; }

// ---------------------------------------------------------------------------
// Kernel 1: cast ALL weights fp32 -> bf16 register-direct tile layout.
// Tile = 256 cols x 32 k of bf16 (8192 u16 = 1024 uint4);
// element (col,k) at uint4 index (col>>4)*64 + (k>>3)*16 + (col&15).
// ---------------------------------------------------------------------------
__global__ void cast_all_kernel(const float* __restrict__ cw3,
                                const float* __restrict__ cw4,
                                const float* __restrict__ cw5,
                                const float* __restrict__ Wih0f,
                                const float* __restrict__ Wih0b,
                                const float* __restrict__ Wih1f,
                                const float* __restrict__ Wih1b,
                                unsigned short* __restrict__ wbc,
                                unsigned short* __restrict__ wih0c,
                                unsigned short* __restrict__ wih1c) {
    int tid = blockIdx.x * blockDim.x + threadIdx.x;
    const float* src;
    uint4* dstp;
    if (tid < 294912) {                       // conv: 12*24*256*4
        int g   = tid & 3;
        int col = (tid >> 2) & 255;
        int c   = (tid >> 10) % 24;
        int p   = tid / (24 * 256 * 4);
        int sz, j; const float* W;
        if (p < 3)      { sz = 3; j = p;     W = cw3; }
        else if (p < 7) { sz = 4; j = p - 3; W = cw4; }
        else            { sz = 5; j = p - 7; W = cw5; }
        src = W + ((size_t)col * sz + j) * 768 + c * 32 + g * 8;
        dstp = reinterpret_cast<uint4*>(wbc) +
               ((size_t)(p * 24 + c) * 1024 + (col >> 4) * 64 + g * 16 + (col & 15));
    } else if (tid < 294912 + 49152) {        // Wih0: 2*24*256*4
        int u   = tid - 294912;
        int g   = u & 3;
        int col = (u >> 2) & 255;
        int kc  = (u >> 10) % 24;
        int dir = u / (24 * 256 * 4);
        const float* W = dir ? Wih0b : Wih0f;
        src = W + (size_t)col * 768 + kc * 32 + g * 8;
        dstp = reinterpret_cast<uint4*>(wih0c) +
               ((size_t)(dir * 24 + kc) * 1024 + (col >> 4) * 64 + g * 16 + (col & 15));
    } else if (tid < 294912 + 49152 + 8192) { // Wih1: 2*4*256*4
        int u   = tid - 294912 - 49152;
        int g   = u & 3;
        int col = (u >> 2) & 255;
        int kc  = (u >> 10) % 4;
        int dir = u / (4 * 256 * 4);
        const float* W = dir ? Wih1b : Wih1f;
        src = W + (size_t)col * 128 + kc * 32 + g * 8;
        dstp = reinterpret_cast<uint4*>(wih1c) +
               ((size_t)(dir * 4 + kc) * 1024 + (col >> 4) * 64 + g * 16 + (col & 15));
    } else return;
    float4 a = *(const float4*)(src);
    float4 b = *(const float4*)(src + 4);
    *dstp = make_uint4(pk2(a.x, a.y), pk2(a.z, a.w), pk2(b.x, b.y), pk2(b.z, b.w));
}

// ---------------------------------------------------------------------------
// Kernel 2: conv via MFMA. Waves own DISJOINT 64-col B quarters (nw=wid),
// each wave covers all 128 rows (acc[8][4]) -> B L1 traffic halved per FLOP.
// B global->register dbuf; X in dbuf LDS; one barrier per c-chunk.
// ---------------------------------------------------------------------------
template<int SZ>
DEV void conv_body(const int* __restrict__ ids,
                   const float* __restrict__ emb,
                   const unsigned short* __restrict__ wbc,
                   const float* __restrict__ cb,
                   unsigned short* __restrict__ para_bf,
                   int pair, int szi, int pbase,
                   unsigned short* Xlds)
{
    int tid  = threadIdx.x;
    int lane = tid & 63;
    int nw   = tid >> 6;        // 0..3: 64-col quarter
    int l15  = lane & 15;
    int q    = lane >> 4;
    int n0   = pair * 2;

    int srow  = tid >> 1;       // 0..127
    int shalf = tid & 1;
    int sid   = ids[(n0 + (srow >> 6)) * 64 + (srow & 63)];
    const float* embrow = emb + (size_t)sid * 768 + shalf * 16;
    int skey = (srow >> 1) & 3;
    int xo0 = srow * 32 + (((2 * shalf)     ^ skey) * 8);
    int xo1 = srow * 32 + (((2 * shalf + 1) ^ skey) * 8);

    int vlaneB = nw * 2048 + lane * 8;     // u16 units, quarter base

    f32x4 acc[8][4];
    #pragma unroll
    for (int a = 0; a < 8; a++)
        #pragma unroll
        for (int t = 0; t < 4; t++) acc[a][t] = (f32x4){0.f, 0.f, 0.f, 0.f};

    bf16x8 bfr[2][4];
    float4 e0, e1, e2, e3;

    // prologue: e(c=0), bfr[0] <= tile pbase*24, pack X buf0, barrier
    {
        e0 = ((const float4*)embrow)[0];
        e1 = ((const float4*)embrow)[1];
        e2 = ((const float4*)embrow)[2];
        e3 = ((const float4*)embrow)[3];
        const unsigned short* bt = wbc + (size_t)(pbase * 24) * 8192 + vlaneB;
        #pragma unroll
        for (int t = 0; t < 4; t++)
            bfr[0][t] = *(const bf16x8*)(bt + t * 512);
        uint4 p0 = make_uint4(pk2(e0.x, e0.y), pk2(e0.z, e0.w),
                              pk2(e1.x, e1.y), pk2(e1.z, e1.w));
        uint4 p1 = make_uint4(pk2(e2.x, e2.y), pk2(e2.z, e2.w),
                              pk2(e3.x, e3.y), pk2(e3.z, e3.w));
        *(uint4*)&Xlds[xo0] = p0;
        *(uint4*)&Xlds[xo1] = p1;
        asm volatile("s_waitcnt lgkmcnt(0)" ::: "memory");
        __builtin_amdgcn_s_barrier();
    }

    int cbase = pbase * 24;    // uniform tile base, advances by 2 per c2
    for (int c2 = 0; c2 < 24; c2 += 2, cbase += 2) {
        #pragma unroll
        for (int s2 = 0; s2 < 2 * SZ; ++s2) {
            const int half = (s2 < SZ) ? 0 : 1;
            const int j    = s2 - half * SZ;
            const int par  = s2 & 1;
            // prefetch B(s2+1): compile-time tile offset from cbase
            {
                const int sP = s2 + 1;
                const int offP = (sP < SZ) ? sP * 24
                               : (sP < 2 * SZ ? (sP - SZ) * 24 + 1 : 2);
                const unsigned short* bt =
                    wbc + (size_t)(cbase + offP) * 8192 + vlaneB;
                #pragma unroll
                for (int t = 0; t < 4; t++)
                    bfr[par ^ 1][t] = *(const bf16x8*)(bt + t * 512);
            }
            if (s2 == 0 || s2 == SZ) {      // emb prefetch for next chunk
                int cE = half ? c2 + 2 : c2 + 1; if (cE > 23) cE = 0;
                const float* sp = embrow + cE * 32;
                e0 = ((const float4*)sp)[0];
                e1 = ((const float4*)sp)[1];
                e2 = ((const float4*)sp)[2];
                e3 = ((const float4*)sp)[3];
            }

            const unsigned short* Xb = Xlds + half * 4096;
            // group 1: rows 0..63 (sentence 0)
            {
                bf16x8 af[4];
                #pragma unroll
                for (int a = 0; a < 4; a++) {
                    int pp = 16 * a + l15 + j; if (pp > 63) pp = 63;
                    af[a] = *(const bf16x8*)(
                        &Xb[pp * 32 + ((q ^ ((pp >> 1) & 3)) * 8)]);
                }
                __builtin_amdgcn_s_setprio(1);
                #pragma unroll
                for (int a = 0; a < 4; a++)
                    #pragma unroll
                    for (int t = 0; t < 4; t++)
                        acc[a][t] = __builtin_amdgcn_mfma_f32_16x16x32_bf16(
                            af[a], bfr[par][t], acc[a][t], 0, 0, 0);
                __builtin_amdgcn_s_setprio(0);
            }
            // group 2: rows 64..127 (sentence 1)
            {
                bf16x8 af[4];
                #pragma unroll
                for (int a = 0; a < 4; a++) {
                    int pp = 16 * a + l15 + j; if (pp > 63) pp = 63;
                    int xr = 64 + pp;
                    af[a] = *(const bf16x8*)(
                        &Xb[xr * 32 + ((q ^ ((xr >> 1) & 3)) * 8)]);
                }
                __builtin_amdgcn_s_setprio(1);
                #pragma unroll
                for (int a = 0; a < 4; a++)
                    #pragma unroll
                    for (int t = 0; t < 4; t++)
                        acc[4 + a][t] = __builtin_amdgcn_mfma_f32_16x16x32_bf16(
                            af[a], bfr[par][t], acc[4 + a][t], 0, 0, 0);
                __builtin_amdgcn_s_setprio(0);
            }

            if (j == SZ - 1) {   // pack X(next chunk) into other buffer
                unsigned short* Xw = Xlds + (half ^ 1) * 4096;
                uint4 p0 = make_uint4(pk2(e0.x, e0.y), pk2(e0.z, e0.w),
                                      pk2(e1.x, e1.y), pk2(e1.z, e1.w));
                uint4 p1 = make_uint4(pk2(e2.x, e2.y), pk2(e2.z, e2.w),
                                      pk2(e3.x, e3.y), pk2(e3.z, e3.w));
                *(uint4*)&Xw[xo0] = p0;
                *(uint4*)&Xw[xo1] = p1;
                asm volatile("s_waitcnt lgkmcnt(0)" ::: "memory");
                __builtin_amdgcn_s_barrier();
            }
        }
    }

    // epilogue: relu(acc+bias), mask, maxpool, store bf16 rows t*8+b
    int pmax = 64 - SZ;
    #pragma unroll
    for (int t = 0; t < 4; t++) {
        int colb = nw * 64 + t * 16;
        float bias = cb[colb + l15];
        #pragma unroll
        for (int s = 0; s < 2; s++) {
            float m = 0.0f;
            #pragma unroll
            for (int a4 = 0; a4 < 4; a4++) {
                #pragma unroll
                for (int r = 0; r < 4; r++) {
                    int p = 16 * a4 + q * 4 + r;
                    float v = acc[s * 4 + a4][t][r] + bias;
                    v = v > 0.f ? v : 0.f;
                    if (p <= pmax) m = v > m ? v : m;
                }
            }
            m = fmaxf(m, __shfl_xor(m, 16));
            m = fmaxf(m, __shfl_xor(m, 32));
            if (lane < 16) {
                int n = n0 + s;
                int row = (n & 63) * 8 + (n >> 6);     // t*8 + b
                para_bf[(size_t)row * 768 + szi * 256 + colb + lane] =
                    (unsigned short)f2bf(m);
            }
        }
    }
}

__global__ __launch_bounds__(256, 2) void conv_pool_kernel(
    const int* __restrict__ ids,
    const float* __restrict__ emb,
    const unsigned short* __restrict__ wbc,
    const float* __restrict__ cb3, const float* __restrict__ cb4,
    const float* __restrict__ cb5,
    unsigned short* __restrict__ para_bf)
{
    __shared__ unsigned short Xlds[2][4096];
    int bx   = blockIdx.x;
    int szi  = bx >> 8;
    int pair = bx & 255;
    if (szi == 0)
        conv_body<3>(ids, emb, wbc, cb3, para_bf, pair, 0, 0, &Xlds[0][0]);
    else if (szi == 1)
        conv_body<4>(ids, emb, wbc, cb4, para_bf, pair, 1, 3, &Xlds[0][0]);
    else
        conv_body<5>(ids, emb, wbc, cb5, para_bf, pair, 2, 7, &Xlds[0][0]);
}

// ---------------------------------------------------------------------------
// Kernel 3: LSTM input projection via MFMA, no LDS, no barriers.
// ---------------------------------------------------------------------------
template<int KC>
__global__ __launch_bounds__(256) void gemm_in_kernel(
    const unsigned short* __restrict__ xbf,   // [512][KC*32]
    const unsigned short* __restrict__ wihc,  // [2*KC] tiles
    const float* __restrict__ bihF, const float* __restrict__ bhhF,
    const float* __restrict__ bihB, const float* __restrict__ bhhB,
    float* __restrict__ gates)                // [2][256][512]
{
    const int din = KC * 32;
    int bx   = blockIdx.x;
    int dir  = bx >> 3;
    int rowg = (bx >> 1) & 3;
    int colg = bx & 1;
    int tid  = threadIdx.x;
    int lane = tid & 63;
    int wid  = tid >> 6;
    int mw   = wid >> 1;
    int nw   = wid & 1;
    int l15  = lane & 15;
    int q    = lane >> 4;

    const float* bih = dir ? bihB : bihF;
    const float* bhh = dir ? bhhB : bhhF;
    const unsigned short* wt = wihc + (size_t)dir * KC * 8192;

    const unsigned short* arow[4];
    #pragma unroll
    for (int a = 0; a < 4; a++)
        arow[a] = xbf + (size_t)(rowg * 128 + mw * 64 + a * 16 + l15) * din + q * 8;
    const unsigned short* bbase = wt + (colg * 8 + nw * 4) * 512 + lane * 8;

    f32x4 acc[4][4];
    #pragma unroll
    for (int a = 0; a < 4; a++)
        #pragma unroll
        for (int t = 0; t < 4; t++) acc[a][t] = (f32x4){0.f, 0.f, 0.f, 0.f};

    bf16x8 afb[2][4], bfb[2][4];
    #pragma unroll
    for (int a = 0; a < 4; a++) afb[0][a] = *(const bf16x8*)(arow[a]);
    #pragma unroll
    for (int t = 0; t < 4; t++) bfb[0][t] = *(const bf16x8*)(bbase + t * 512);

    #pragma unroll 2
    for (int kc = 0; kc < KC; ++kc) {
        const int p = kc & 1;
        int kn = (kc + 1 < KC) ? kc + 1 : kc;
        #pragma unroll
        for (int a = 0; a < 4; a++)
            afb[p ^ 1][a] = *(const bf16x8*)(arow[a] + kn * 32);
        #pragma unroll
        for (int t = 0; t < 4; t++)
            bfb[p ^ 1][t] = *(const bf16x8*)(bbase + (size_t)kn * 8192 + t * 512);
        __builtin_amdgcn_s_setprio(1);
        #pragma unroll
        for (int a = 0; a < 4; a++)
            #pragma unroll
            for (int t = 0; t < 4; t++)
                acc[a][t] = __builtin_amdgcn_mfma_f32_16x16x32_bf16(
                    afb[p][a], bfb[p][t], acc[a][t], 0, 0, 0);
        __builtin_amdgcn_s_setprio(0);
    }

    #pragma unroll
    for (int t = 0; t < 4; t++) {
        int nn = colg * 128 + nw * 64 + t * 16 + l15;
        float bb = bih[nn] + bhh[nn];
        float* gp = gates + ((size_t)dir * 256 + nn) * 512 +
                    rowg * 128 + mw * 64 + q * 4;
        #pragma unroll
        for (int a = 0; a < 4; a++) {
            f32x4 v = acc[a][t];
            v[0] += bb; v[1] += bb; v[2] += bb; v[3] += bb;
            *(f32x4*)(gp + a * 16) = v;
        }
    }
}

// ---------------------------------------------------------------------------
// Kernel 4: LSTM recurrence via MFMA. 1 block/dir, 256 threads (4 waves).
// houtF may be null (layer 0: fp32 h unused downstream).
// ---------------------------------------------------------------------------
__global__ __launch_bounds__(256) void lstm_rec_kernel(
    const float* __restrict__ gates,    // (2,256,512)
    const float* __restrict__ WhhF, const float* __restrict__ WhhB, // (256,64)
    float* __restrict__ houtF,          // (64,8,128) or null
    unsigned short* __restrict__ houtB) // (64,8,128) bf16
{
    int dir = blockIdx.x;
    const float* Whh = dir ? WhhB : WhhF;
    const float* gin = gates + (size_t)dir * 256 * 512;

    __shared__ unsigned short h16[2][16 * 64];

    int tid  = threadIdx.x;
    int lane = tid & 63;
    int w    = tid >> 6;
    int l15  = lane & 15;
    int q    = lane >> 4;
    int hh   = 16 * w + l15;

    bf16x8 Bf[4][2];
    #pragma unroll
    for (int g = 0; g < 4; g++)
        #pragma unroll
        for (int kh = 0; kh < 2; kh++) {
            const float* wp = Whh + (size_t)(g * 64 + hh) * 64 + kh * 32 + q * 8;
            float4 f0 = *(const float4*)wp;
            float4 f1 = *(const float4*)(wp + 4);
            bf16x8 r;
            r[0] = (__bf16)f0.x; r[1] = (__bf16)f0.y;
            r[2] = (__bf16)f0.z; r[3] = (__bf16)f0.w;
            r[4] = (__bf16)f1.x; r[5] = (__bf16)f1.y;
            r[6] = (__bf16)f1.z; r[7] = (__bf16)f1.w;
            Bf[g][kh] = r;
        }

    const float* pg0 = gin + ((size_t)(0 * 64 + hh)) * 512 + 4 * (q & 1);
    const float* pg1 = gin + ((size_t)(1 * 64 + hh)) * 512 + 4 * (q & 1);
    const float* pg2 = gin + ((size_t)(2 * 64 + hh)) * 512 + 4 * (q & 1);
    const float* pg3 = gin + ((size_t)(3 * 64 + hh)) * 512 + 4 * (q & 1);

    for (int i = tid; i < 2 * 16 * 64; i += 256)
        ((unsigned short*)h16)[i] = 0;
    float cst[4] = {0.f, 0.f, 0.f, 0.f};
    __syncthreads();

    int t0 = dir ? 63 : 0;
    f32x4 gv0 = *(const f32x4*)(pg0 + t0 * 8);
    f32x4 gv1 = *(const f32x4*)(pg1 + t0 * 8);
    f32x4 gv2 = *(const f32x4*)(pg2 + t0 * 8);
    f32x4 gv3 = *(const f32x4*)(pg3 + t0 * 8);

    for (int s = 0; s < 64; ++s) {
        int t = dir ? 63 - s : s;
        const unsigned short* hb = h16[s & 1];
        int slot0 = q ^ (l15 & 7);
        int slot1 = (4 + q) ^ (l15 & 7);
        bf16x8 a0 = *(const bf16x8*)&hb[l15 * 64 + slot0 * 8];
        bf16x8 a1 = *(const bf16x8*)&hb[l15 * 64 + slot1 * 8];

        f32x4 zero = (f32x4){0.f, 0.f, 0.f, 0.f};
        f32x4 acc[4];
        #pragma unroll
        for (int g = 0; g < 4; g++) {
            acc[g] = __builtin_amdgcn_mfma_f32_16x16x32_bf16(a0, Bf[g][0], zero, 0, 0, 0);
            acc[g] = __builtin_amdgcn_mfma_f32_16x16x32_bf16(a1, Bf[g][1], acc[g], 0, 0, 0);
        }

        int sn = (s + 1 < 64) ? s + 1 : 63;
        int t2 = dir ? 63 - sn : sn;
        f32x4 n0 = *(const f32x4*)(pg0 + t2 * 8);
        f32x4 n1 = *(const f32x4*)(pg1 + t2 * 8);
        f32x4 n2 = *(const f32x4*)(pg2 + t2 * 8);
        f32x4 n3 = *(const f32x4*)(pg3 + t2 * 8);

        if (q < 2) {
            unsigned short* hw = h16[(s + 1) & 1];
            #pragma unroll
            for (int r = 0; r < 4; r++) {
                int b = 4 * q + r;
                float gi = acc[0][r] + gv0[r];
                float gf = acc[1][r] + gv1[r];
                float gg = acc[2][r] + gv2[r];
                float go = acc[3][r] + gv3[r];
                float cn = sigf(gf) * cst[r] + sigf(gi) * tanhff(gg);
                float hv = sigf(go) * tanhff(cn);
                cst[r] = cn;
                int slot = (hh >> 3) ^ (b & 7);
                hw[b * 64 + slot * 8 + (hh & 7)] = (unsigned short)f2bf(hv);
                size_t oi = ((size_t)t * 8 + b) * 128 + dir * 64 + hh;
                if (houtF) houtF[oi] = hv;
                houtB[oi] = (unsigned short)f2bf(hv);
            }
        }
        __syncthreads();
        gv0 = n0; gv1 = n1; gv2 = n2; gv3 = n3;
    }
}

// ---------------------------------------------------------------------------
// Kernel 5: feats + CRF scan + gold, single block, LDS-staged
// ---------------------------------------------------------------------------
__global__ __launch_bounds__(512) void crf_kernel(
    const float* __restrict__ h1,       // (64,8,128)
    const float* __restrict__ lin_w,    // (5,128)
    const float* __restrict__ lin_b,    // (5)
    const float* __restrict__ mask,     // (64,8)
    const int* __restrict__ tags,       // (64,8)
    const float* __restrict__ trans,    // (5,5)
    float* __restrict__ out) {
    __shared__ float feats[64][8][5];
    __shared__ float wl[5][128];
    __shared__ float msk[512];
    __shared__ int   tgs[512];
    __shared__ float fwd_s[8], gold_s[8];
    __shared__ float tr[25], trE[5], lb[5];
    int tid = threadIdx.x;
    if (tid < 25) tr[tid] = trans[tid];
    if (tid < 5) { trE[tid] = trans[20 + tid]; lb[tid] = lin_b[tid]; }
    msk[tid] = mask[tid];
    tgs[tid] = tags[tid];
    if (tid < 128) {
        #pragma unroll
        for (int i = 0; i < 5; i++) wl[i][tid] = lin_w[i * 128 + tid];
    }
    __syncthreads();

    {
        const float4* h4 = (const float4*)(h1 + (size_t)tid * 128);
        float a0 = 0.f, a1 = 0.f, a2 = 0.f, a3 = 0.f, a4 = 0.f;
        for (int e4 = 0; e4 < 32; e4++) {
            float4 hv = h4[e4];
            int e = e4 * 4;
            a0 += hv.x * wl[0][e] + hv.y * wl[0][e+1] + hv.z * wl[0][e+2] + hv.w * wl[0][e+3];
            a1 += hv.x * wl[1][e] + hv.y * wl[1][e+1] + hv.z * wl[1][e+2] + hv.w * wl[1][e+3];
            a2 += hv.x * wl[2][e] + hv.y * wl[2][e+1] + hv.z * wl[2][e+2] + hv.w * wl[2][e+3];
            a3 += hv.x * wl[3][e] + hv.y * wl[3][e+1] + hv.z * wl[3][e+2] + hv.w * wl[3][e+3];
            a4 += hv.x * wl[4][e] + hv.y * wl[4][e+1] + hv.z * wl[4][e+2] + hv.w * wl[4][e+3];
        }
        float m = msk[tid];
        int t = tid >> 3, b = tid & 7;
        feats[t][b][0] = (m * a0 + lb[0]) * m;
        feats[t][b][1] = (m * a1 + lb[1]) * m;
        feats[t][b][2] = (m * a2 + lb[2]) * m;
        feats[t][b][3] = (m * a3 + lb[3]) * m;
        feats[t][b][4] = (m * a4 + lb[4]) * m;
    }
    __syncthreads();

    if (tid < 40) {    // wave 0, lane = b*5+i
        int b = tid / 5, i = tid % 5;
        float alpha = (i == 0) ? 0.f : NEG_VAL;
        float trow[5];
        #pragma unroll
        for (int j2 = 0; j2 < 5; j2++) trow[j2] = tr[i * 5 + j2];
        for (int t = 0; t < 64; t++) {
            float s0, s1, s2, s3, s4;
            s0 = __shfl(alpha, b * 5 + 0, 64) + trow[0];
            s1 = __shfl(alpha, b * 5 + 1, 64) + trow[1];
            s2 = __shfl(alpha, b * 5 + 2, 64) + trow[2];
            s3 = __shfl(alpha, b * 5 + 3, 64) + trow[3];
            s4 = __shfl(alpha, b * 5 + 4, 64) + trow[4];
            float mx = fmaxf(fmaxf(fmaxf(s0, s1), fmaxf(s2, s3)), s4);
            float sum = expf(s0 - mx) + expf(s1 - mx) + expf(s2 - mx) +
                        expf(s3 - mx) + expf(s4 - mx);
            float lse = mx + logf(sum) + feats[t][b][i];
            float mt = msk[t * 8 + b];
            alpha = mt * lse + (1.f - mt) * alpha;
        }
        float v = alpha + trE[i];
        float m0 = __shfl(v, b * 5 + 0, 64);
        float m1 = __shfl(v, b * 5 + 1, 64);
        float m2 = __shfl(v, b * 5 + 2, 64);
        float m3 = __shfl(v, b * 5 + 3, 64);
        float m4 = __shfl(v, b * 5 + 4, 64);
        float mx = fmaxf(fmaxf(fmaxf(m0, m1), fmaxf(m2, m3)), m4);
        float sum = expf(m0 - mx) + expf(m1 - mx) + expf(m2 - mx) +
                    expf(m3 - mx) + expf(m4 - mx);
        if (i == 0) fwd_s[b] = mx + logf(sum);
    }
    if (tid >= 64 && tid < 72) {
        int b = tid - 64;
        float g = 0.f, lenf = 0.f;
        int prev = 0;   // SOS
        for (int t = 0; t < 64; t++) {
            int tg = tgs[t * 8 + b];
            float mt = msk[t * 8 + b];
            g += (feats[t][b][tg] + tr[tg * 5 + prev]) * mt;
            lenf += mt;
            prev = tg;
        }
        int len = (int)lenf;
        int last = (len == 0) ? 0 : tgs[(len - 1) * 8 + b];
        g += trE[last];
        gold_s[b] = g;
    }
    __syncthreads();
    if (tid == 0) {
        float s = 0.f;
        for (int b = 0; b < 8; b++) s += fwd_s[b] - gold_s[b];
        out[0] = s;
    }
}

// ---------------------------------------------------------------------------
extern "C" void kernel_launch(void* const* d_in, const int* in_sizes, int n_in,
                              void* d_out, int out_size, void* d_ws, size_t ws_size,
                              hipStream_t stream) {
    const int*   ids   = (const int*)d_in[0];
    const int*   tags  = (const int*)d_in[1];
    const float* mask  = (const float*)d_in[2];
    const float* emb   = (const float*)d_in[4];
    const float* cw3   = (const float*)d_in[5];
    const float* cb3   = (const float*)d_in[6];
    const float* cw4   = (const float*)d_in[7];
    const float* cb4   = (const float*)d_in[8];
    const float* cw5   = (const float*)d_in[9];
    const float* cb5   = (const float*)d_in[10];
    const float* Wih0f = (const float*)d_in[11];
    const float* Whh0f = (const float*)d_in[12];
    const float* bih0f = (const float*)d_in[13];
    const float* bhh0f = (const float*)d_in[14];
    const float* Wih0b = (const float*)d_in[15];
    const float* Whh0b = (const float*)d_in[16];
    const float* bih0b = (const float*)d_in[17];
    const float* bhh0b = (const float*)d_in[18];
    const float* Wih1f = (const float*)d_in[19];
    const float* Whh1f = (const float*)d_in[20];
    const float* bih1f = (const float*)d_in[21];
    const float* bhh1f = (const float*)d_in[22];
    const float* Wih1b = (const float*)d_in[23];
    const float* Whh1b = (const float*)d_in[24];
    const float* bih1b = (const float*)d_in[25];
    const float* bhh1b = (const float*)d_in[26];
    const float* lin_w = (const float*)d_in[27];
    const float* lin_b = (const float*)d_in[28];
    const float* trans = (const float*)d_in[29];

    char* ws = (char*)d_ws;
    unsigned short* wbc     = (unsigned short*)ws;
    unsigned short* wih0c   = (unsigned short*)(ws + 4718592);
    unsigned short* wih1c   = (unsigned short*)(ws + 5505024);
    unsigned short* para_bf = (unsigned short*)(ws + 5636096);
    float*          gates   = (float*)(ws + 6422528);
    unsigned short* h0_bf   = (unsigned short*)(ws + 5636096);
    float*          h1f     = (float*)(ws + 4718592);

    hipLaunchKernelGGL(cast_all_kernel, dim3(1376), dim3(256), 0, stream,
                       cw3, cw4, cw5, Wih0f, Wih0b, Wih1f, Wih1b,
                       wbc, wih0c, wih1c);
    hipLaunchKernelGGL(conv_pool_kernel, dim3(768), dim3(256), 0, stream,
                       ids, emb, wbc, cb3, cb4, cb5, para_bf);
    hipLaunchKernelGGL((gemm_in_kernel<24>), dim3(16), dim3(256), 0, stream,
                       para_bf, wih0c, bih0f, bhh0f, bih0b, bhh0b, gates);
    hipLaunchKernelGGL(lstm_rec_kernel, dim3(2), dim3(256), 0, stream,
                       gates, Whh0f, Whh0b, (float*)nullptr, h0_bf);
    hipLaunchKernelGGL((gemm_in_kernel<4>), dim3(16), dim3(256), 0, stream,
                       h0_bf, wih1c, bih1f, bhh1f, bih1b, bhh1b, gates);
    hipLaunchKernelGGL(lstm_rec_kernel, dim3(2), dim3(256), 0, stream,
                       gates, Whh1f, Whh1b, h1f, h0_bf);
    hipLaunchKernelGGL(crf_kernel, dim3(1), dim3(512), 0, stream,
                       h1f, lin_w, lin_b, mask, tags, trans, (float*)d_out);
}